// Round 1
// baseline (7343.040 us; speedup 1.0000x reference)
//
#include <hip/hip_runtime.h>
#include <math.h>

#define H 128
#define I_DIM 128
#define T_STEPS 30
#define M_MODES 6
#define N_AG 8192
#define B_TOT (M_MODES * N_AG)   /* 49152 */
#define ROWS 16
#define LN_EPS 1e-5f
#define MIN_SCALE 0.001f

__device__ __forceinline__ float dot4(float4 a, float4 b) {
    return a.x * b.x + a.y * b.y + a.z * b.z + a.w * b.w;
}

__device__ __forceinline__ float wave_sum(float v) {
    #pragma unroll
    for (int off = 32; off > 0; off >>= 1) v += __shfl_xor(v, off);
    return v;
}

__device__ __forceinline__ float sigm(float x) {
    return 1.0f / (1.0f + expf(-x));
}

// ---------------------------------------------------------------------------
// GRU + loc/scale heads. One block = 16 rows of B = M*N. 128 threads.
// Thread j owns hidden channel j (gates r,z,n = W rows j, j+128, j+256).
// ---------------------------------------------------------------------------
__global__ __launch_bounds__(128) void gru_heads_kernel(
    const float* __restrict__ local_embed,   // [N, H]
    const float* __restrict__ global_embed,  // [B, I]
    const float* __restrict__ W_ih,          // [3H, I]
    const float* __restrict__ W_hh,          // [3H, H]
    const float* __restrict__ b_ih,          // [3H]
    const float* __restrict__ b_hh,          // [3H]
    const float* __restrict__ loc1_w,        // [H, H]
    const float* __restrict__ loc1_b,        // [H]
    const float* __restrict__ loc_ln_g, const float* __restrict__ loc_ln_b,
    const float* __restrict__ loc2_w,        // [2, H]
    const float* __restrict__ loc2_b,        // [2]
    const float* __restrict__ sc1_w, const float* __restrict__ sc1_b,
    const float* __restrict__ sc_ln_g, const float* __restrict__ sc_ln_b,
    const float* __restrict__ sc2_w, const float* __restrict__ sc2_b,
    float* __restrict__ traj)                // [B, T, 4]
{
    __shared__ float hA[ROWS][H];            // 8 KB
    __shared__ float hB[ROWS][H];            // 8 KB
    __shared__ float lnbuf[ROWS][2][H];      // 16 KB (also x-staging at init)
    __shared__ float red[2][ROWS][2][2];     // [wave][row][head][sum,sumsq]

    const int j    = threadIdx.x;            // 0..127 hidden channel
    const int wid  = j >> 6;                 // wave 0/1
    const int lane = j & 63;
    const int b0   = blockIdx.x * ROWS;

    // ---- stage h0 and x ----
    #pragma unroll
    for (int r = 0; r < ROWS; ++r) {
        const int b = b0 + r;
        const int n = b & (N_AG - 1);
        hA[r][j] = local_embed[(size_t)n * H + j];
        lnbuf[r][0][j] = global_embed[(size_t)b * I_DIM + j];  // x row
    }
    __syncthreads();

    // ---- per-thread constants ----
    const float bhr = b_hh[j], bhz = b_hh[H + j], bhn = b_hh[2 * H + j];
    const float lgj = loc_ln_g[j], lbj = loc_ln_b[j];
    const float sgj = sc_ln_g[j],  sbj = sc_ln_b[j];
    const float l1b = loc1_b[j],   s1b = sc1_b[j];

    // ---- gx = x @ W_ih.T + b_ih : thread-local registers, computed once ----
    float gx0[ROWS], gx1[ROWS], gx2[ROWS];
    #pragma unroll
    for (int r = 0; r < ROWS; ++r) { gx0[r] = 0.f; gx1[r] = 0.f; gx2[r] = 0.f; }
    {
        const float4* u0 = (const float4*)(W_ih + (size_t)j * I_DIM);
        const float4* u1 = (const float4*)(W_ih + (size_t)(H + j) * I_DIM);
        const float4* u2 = (const float4*)(W_ih + (size_t)(2 * H + j) * I_DIM);
        #pragma unroll 4
        for (int k4 = 0; k4 < I_DIM / 4; ++k4) {
            const float4 w0 = u0[k4], w1 = u1[k4], w2 = u2[k4];
            #pragma unroll
            for (int r = 0; r < ROWS; ++r) {
                const float4 xv = ((const float4*)(&lnbuf[r][0][0]))[k4];
                gx0[r] += dot4(w0, xv);
                gx1[r] += dot4(w1, xv);
                gx2[r] += dot4(w2, xv);
            }
        }
        const float bi0 = b_ih[j], bi1 = b_ih[H + j], bi2 = b_ih[2 * H + j];
        #pragma unroll
        for (int r = 0; r < ROWS; ++r) { gx0[r] += bi0; gx1[r] += bi1; gx2[r] += bi2; }
    }

    const float4* w0p = (const float4*)(W_hh + (size_t)j * H);
    const float4* w1p = (const float4*)(W_hh + (size_t)(H + j) * H);
    const float4* w2p = (const float4*)(W_hh + (size_t)(2 * H + j) * H);
    const float4* wlp = (const float4*)(loc1_w + (size_t)j * H);
    const float4* wsp = (const float4*)(sc1_w + (size_t)j * H);

    for (int t = 0; t < T_STEPS; ++t) {
        float* hc = (t & 1) ? &hB[0][0] : &hA[0][0];
        float* hn = (t & 1) ? &hA[0][0] : &hB[0][0];

        // ---- gh = h @ W_hh.T ----
        float ar[ROWS], az[ROWS], an[ROWS];
        #pragma unroll
        for (int r = 0; r < ROWS; ++r) { ar[r] = 0.f; az[r] = 0.f; an[r] = 0.f; }
        #pragma unroll 4
        for (int k4 = 0; k4 < H / 4; ++k4) {
            const float4 w0 = w0p[k4], w1 = w1p[k4], w2 = w2p[k4];
            #pragma unroll
            for (int r = 0; r < ROWS; ++r) {
                const float4 hv = ((const float4*)(hc + r * H))[k4];
                ar[r] += dot4(w0, hv);
                az[r] += dot4(w1, hv);
                an[r] += dot4(w2, hv);
            }
        }

        // ---- gates (thread-local) ----
        #pragma unroll
        for (int r = 0; r < ROWS; ++r) {
            const float rr = sigm(gx0[r] + ar[r] + bhr);
            const float zz = sigm(gx1[r] + az[r] + bhz);
            const float nn = tanhf(gx2[r] + rr * (an[r] + bhn));
            const float hold = hc[r * H + j];
            hn[r * H + j] = (1.f - zz) * nn + zz * hold;
        }
        __syncthreads();   // SYNC_A: h_new visible

        // ---- loc1 / sc1 dots ----
        float aL[ROWS], aS[ROWS];
        #pragma unroll
        for (int r = 0; r < ROWS; ++r) { aL[r] = l1b; aS[r] = s1b; }
        #pragma unroll 4
        for (int k4 = 0; k4 < H / 4; ++k4) {
            const float4 wl = wlp[k4], ws = wsp[k4];
            #pragma unroll
            for (int r = 0; r < ROWS; ++r) {
                const float4 hv = ((const float4*)(hn + r * H))[k4];
                aL[r] += dot4(wl, hv);
                aS[r] += dot4(ws, hv);
            }
        }

        // ---- LayerNorm reductions ----
        #pragma unroll
        for (int r = 0; r < ROWS; ++r) {
            const float sL = wave_sum(aL[r]);
            const float qL = wave_sum(aL[r] * aL[r]);
            const float sS = wave_sum(aS[r]);
            const float qS = wave_sum(aS[r] * aS[r]);
            if (lane == 0) {
                red[wid][r][0][0] = sL; red[wid][r][0][1] = qL;
                red[wid][r][1][0] = sS; red[wid][r][1][1] = qS;
            }
        }
        __syncthreads();   // SYNC_B: partials visible

        #pragma unroll
        for (int r = 0; r < ROWS; ++r) {
            const float sL = red[0][r][0][0] + red[1][r][0][0];
            const float qL = red[0][r][0][1] + red[1][r][0][1];
            const float mL = sL * (1.f / H);
            const float vL = qL * (1.f / H) - mL * mL;
            lnbuf[r][0][j] = fmaxf((aL[r] - mL) * rsqrtf(vL + LN_EPS) * lgj + lbj, 0.f);
            const float sS = red[0][r][1][0] + red[1][r][1][0];
            const float qS = red[0][r][1][1] + red[1][r][1][1];
            const float mS = sS * (1.f / H);
            const float vS = qS * (1.f / H) - mS * mS;
            lnbuf[r][1][j] = fmaxf((aS[r] - mS) * rsqrtf(vS + LN_EPS) * sgj + sbj, 0.f);
        }
        __syncthreads();   // SYNC_C: relu(LN(.)) visible

        // ---- final 2-wide dots + ELU + store (64 threads: r x o) ----
        if (threadIdx.x < ROWS * 4) {
            const int r = threadIdx.x >> 2;
            const int o = threadIdx.x & 3;
            const int head = (o >> 1);                 // 0=loc, 1=sc
            const int oo = o & 1;
            const float* w = head ? (sc2_w + oo * H) : (loc2_w + oo * H);
            const float4* w4 = (const float4*)w;
            const float4* v4 = (const float4*)(&lnbuf[r][head][0]);
            float acc = 0.f;
            #pragma unroll
            for (int k4 = 0; k4 < H / 4; ++k4) acc += dot4(w4[k4], v4[k4]);
            acc += head ? sc2_b[oo] : loc2_b[oo];
            if (head) {
                acc = (acc > 0.f ? acc : expm1f(acc)) + 1.0f + MIN_SCALE;  // elu+1+min_scale
            }
            traj[((size_t)(b0 + r) * T_STEPS + t) * 4 + o] = acc;
        }
        // next-iter barriers protect lnbuf/h reuse
    }
}

// ---------------------------------------------------------------------------
// pi head: [B,256] -> 128 -> LN -> relu -> 128 -> LN -> relu -> 1
// block = 512 threads = 4 rows x 128 channels
// ---------------------------------------------------------------------------
__global__ __launch_bounds__(512) void pi_kernel(
    const float* __restrict__ local_embed,   // [N, H]
    const float* __restrict__ global_embed,  // [B, I]
    const float* __restrict__ pi1_w,         // [H, 2H]
    const float* __restrict__ pi1_b,
    const float* __restrict__ ln1_g, const float* __restrict__ ln1_b,
    const float* __restrict__ pi2_w,         // [H, H]
    const float* __restrict__ pi2_b,
    const float* __restrict__ ln2_g, const float* __restrict__ ln2_b,
    const float* __restrict__ pi3_w,         // [1, H]
    const float* __restrict__ pi3_b,
    float* __restrict__ pi_out)              // [N, M]
{
    __shared__ float inbuf[4][2 * H];        // 4 KB
    __shared__ float h1[4][H];               // 2 KB
    __shared__ float red[4][2][2];

    const int g = threadIdx.x >> 7;          // row group 0..3
    const int j = threadIdx.x & (H - 1);     // channel
    const int w = (threadIdx.x >> 6) & 1;    // wave within group
    const int lane = threadIdx.x & 63;
    const int b = blockIdx.x * 4 + g;
    const int n = b & (N_AG - 1);
    const int m = b >> 13;

    // stage input row: [local(128) | global(128)]
    inbuf[g][j]     = local_embed[(size_t)n * H + j];
    inbuf[g][H + j] = global_embed[(size_t)b * I_DIM + j];
    __syncthreads();

    // layer 1: dot-256
    float acc = pi1_b[j];
    {
        const float4* w4 = (const float4*)(pi1_w + (size_t)j * 2 * H);
        const float4* in4 = (const float4*)(&inbuf[g][0]);
        #pragma unroll 4
        for (int k4 = 0; k4 < 2 * H / 4; ++k4) acc += dot4(w4[k4], in4[k4]);
    }
    // LN1 over 128 channels (2 waves per group)
    {
        const float s = wave_sum(acc);
        const float q = wave_sum(acc * acc);
        if (lane == 0) { red[g][w][0] = s; red[g][w][1] = q; }
    }
    __syncthreads();
    {
        const float s = red[g][0][0] + red[g][1][0];
        const float q = red[g][0][1] + red[g][1][1];
        const float mu = s * (1.f / H);
        const float var = q * (1.f / H) - mu * mu;
        h1[g][j] = fmaxf((acc - mu) * rsqrtf(var + LN_EPS) * ln1_g[j] + ln1_b[j], 0.f);
    }
    __syncthreads();   // h1 ready; red reads done

    // layer 2: dot-128
    float acc2 = pi2_b[j];
    {
        const float4* w4 = (const float4*)(pi2_w + (size_t)j * H);
        const float4* h4 = (const float4*)(&h1[g][0]);
        #pragma unroll 4
        for (int k4 = 0; k4 < H / 4; ++k4) acc2 += dot4(w4[k4], h4[k4]);
    }
    {
        const float s = wave_sum(acc2);
        const float q = wave_sum(acc2 * acc2);
        if (lane == 0) { red[g][w][0] = s; red[g][w][1] = q; }
    }
    __syncthreads();
    float v2;
    {
        const float s = red[g][0][0] + red[g][1][0];
        const float q = red[g][0][1] + red[g][1][1];
        const float mu = s * (1.f / H);
        const float var = q * (1.f / H) - mu * mu;
        v2 = fmaxf((acc2 - mu) * rsqrtf(var + LN_EPS) * ln2_g[j] + ln2_b[j], 0.f);
    }

    // pi3: dot-128 reduce
    const float part = wave_sum(v2 * pi3_w[j]);
    __syncthreads();   // LN2 red reads complete before rewrite
    if (lane == 0) red[g][w][0] = part;
    __syncthreads();
    if (j == 0) pi_out[(size_t)n * M_MODES + m] = red[g][0][0] + red[g][1][0] + pi3_b[0];
}

extern "C" void kernel_launch(void* const* d_in, const int* in_sizes, int n_in,
                              void* d_out, int out_size, void* d_ws, size_t ws_size,
                              hipStream_t stream) {
    (void)in_sizes; (void)n_in; (void)d_ws; (void)ws_size; (void)out_size;
    const float* local_embed  = (const float*)d_in[0];
    const float* global_embed = (const float*)d_in[1];
    const float* W_ih   = (const float*)d_in[2];
    const float* W_hh   = (const float*)d_in[3];
    const float* b_ih   = (const float*)d_in[4];
    const float* b_hh   = (const float*)d_in[5];
    const float* loc1_w = (const float*)d_in[6];
    const float* loc1_b = (const float*)d_in[7];
    const float* loc_ln_g = (const float*)d_in[8];
    const float* loc_ln_b = (const float*)d_in[9];
    const float* loc2_w = (const float*)d_in[10];
    const float* loc2_b = (const float*)d_in[11];
    const float* sc1_w  = (const float*)d_in[12];
    const float* sc1_b  = (const float*)d_in[13];
    const float* sc_ln_g = (const float*)d_in[14];
    const float* sc_ln_b = (const float*)d_in[15];
    const float* sc2_w  = (const float*)d_in[16];
    const float* sc2_b  = (const float*)d_in[17];
    const float* pi1_w  = (const float*)d_in[18];
    const float* pi1_b  = (const float*)d_in[19];
    const float* pi_ln1_g = (const float*)d_in[20];
    const float* pi_ln1_b = (const float*)d_in[21];
    const float* pi2_w  = (const float*)d_in[22];
    const float* pi2_b  = (const float*)d_in[23];
    const float* pi_ln2_g = (const float*)d_in[24];
    const float* pi_ln2_b = (const float*)d_in[25];
    const float* pi3_w  = (const float*)d_in[26];
    const float* pi3_b  = (const float*)d_in[27];

    float* traj = (float*)d_out;
    float* pi_out = traj + (size_t)B_TOT * T_STEPS * 4;

    pi_kernel<<<B_TOT / 4, 512, 0, stream>>>(
        local_embed, global_embed, pi1_w, pi1_b, pi_ln1_g, pi_ln1_b,
        pi2_w, pi2_b, pi_ln2_g, pi_ln2_b, pi3_w, pi3_b, pi_out);

    gru_heads_kernel<<<B_TOT / ROWS, 128, 0, stream>>>(
        local_embed, global_embed, W_ih, W_hh, b_ih, b_hh,
        loc1_w, loc1_b, loc_ln_g, loc_ln_b, loc2_w, loc2_b,
        sc1_w, sc1_b, sc_ln_g, sc_ln_b, sc2_w, sc2_b, traj);
}

// Round 2
// 2097.350 us; speedup vs baseline: 3.5011x; 3.5011x over previous
//
#include <hip/hip_runtime.h>
#include <math.h>

#define H 128
#define I_DIM 128
#define T_STEPS 30
#define M_MODES 6
#define N_AG 8192
#define B_TOT (M_MODES * N_AG)   /* 49152 */
#define ROWS 16
#define LN_EPS 1e-5f
#define MIN_SCALE 0.001f

typedef short bf16x8 __attribute__((ext_vector_type(8)));
typedef float f32x4 __attribute__((ext_vector_type(4)));

#define MFMA16x16x32(A, B, C) __builtin_amdgcn_mfma_f32_16x16x32_bf16(A, B, C, 0, 0, 0)

__device__ __forceinline__ short f2b(float f) {
    union { float f; unsigned u; } v; v.f = f;
    return (short)((v.u + 0x7FFFu + ((v.u >> 16) & 1u)) >> 16);
}

__device__ __forceinline__ bf16x8 load8_cvt(const float* __restrict__ p) {
    const float4 a = ((const float4*)p)[0];
    const float4 b = ((const float4*)p)[1];
    bf16x8 r;
    r[0]=f2b(a.x); r[1]=f2b(a.y); r[2]=f2b(a.z); r[3]=f2b(a.w);
    r[4]=f2b(b.x); r[5]=f2b(b.y); r[6]=f2b(b.z); r[7]=f2b(b.w);
    return r;
}

__device__ __forceinline__ float fast_sigm(float x) {
    return __builtin_amdgcn_rcpf(1.f + __expf(-x));
}
__device__ __forceinline__ float fast_tanh(float x) {
    return 1.f - 2.f * __builtin_amdgcn_rcpf(1.f + __expf(2.f * x));
}

__device__ __forceinline__ float dot4(float4 a, float4 b) {
    return a.x * b.x + a.y * b.y + a.z * b.z + a.w * b.w;
}

__device__ __forceinline__ float wave_sum(float v) {
    #pragma unroll
    for (int off = 32; off > 0; off >>= 1) v += __shfl_xor(v, off);
    return v;
}

__device__ __forceinline__ float sigm(float x) {
    return 1.0f / (1.0f + expf(-x));
}

// ===========================================================================
// Kernel A: GRU recurrence via MFMA. 256 thr = 4 waves, 16 rows/block.
// Wave w owns hidden channels [32w,32w+32) of all 3 gates -> gate math is
// register-local in the MFMA D-layout. Emits bf16 h-history to `hist`.
// ===========================================================================
__global__ __launch_bounds__(256, 2) void gru_rec_kernel(
    const float* __restrict__ local_embed, const float* __restrict__ global_embed,
    const float* __restrict__ W_ih, const float* __restrict__ W_hh,
    const float* __restrict__ b_ih, const float* __restrict__ b_hh,
    int base, unsigned short* __restrict__ hist)
{
    __shared__ short xbuf[16][136];   // padded: row stride 272 B
    __shared__ short hbf[16][136];

    const int tid = threadIdx.x;
    const int w  = tid >> 6;          // wave 0..3
    const int l  = tid & 63;
    const int ln = l & 15;            // lane-in-16 (D col / A row / B col)
    const int lg = l >> 4;            // lane group (D row group / A,B k group)
    const int b0 = base + blockIdx.x * 16;

    // ---- stage x (bf16) and h0 (fp32 regs + bf16 LDS) ----
    float h_reg[2][4];
    #pragma unroll
    for (int u = 0; u < 2; ++u) {
        const int j = 32*w + 16*u + ln;
        #pragma unroll
        for (int rg = 0; rg < 4; ++rg) {
            const int r = lg*4 + rg;
            const int b = b0 + r;
            const int n = b & (N_AG - 1);
            xbuf[r][j] = f2b(global_embed[(size_t)b * I_DIM + j]);
            const float h0 = local_embed[(size_t)n * H + j];
            h_reg[u][rg] = h0;
            hbf[r][j] = f2b(h0);
        }
    }

    // ---- W_ih B-fragments (temporary; overwritten by W_hh below) ----
    bf16x8 wf[3][2][4];
    #pragma unroll
    for (int g = 0; g < 3; ++g)
        #pragma unroll
        for (int u = 0; u < 2; ++u) {
            const int crow = g*H + 32*w + 16*u + ln;
            #pragma unroll
            for (int kt = 0; kt < 4; ++kt)
                wf[g][u][kt] = load8_cvt(W_ih + (size_t)crow * I_DIM + kt*32 + lg*8);
        }

    __syncthreads();

    // ---- gx = x @ W_ih^T + b_ih (once; same input every timestep) ----
    float gx[3][2][4];
    {
        bf16x8 af[4];
        #pragma unroll
        for (int kt = 0; kt < 4; ++kt)
            af[kt] = *(const bf16x8*)&xbuf[ln][kt*32 + lg*8];
        f32x4 acc[3][2];
        #pragma unroll
        for (int g = 0; g < 3; ++g)
            #pragma unroll
            for (int u = 0; u < 2; ++u)
                acc[g][u] = (f32x4)(0.f);
        #pragma unroll
        for (int kt = 0; kt < 4; ++kt)
            #pragma unroll
            for (int g = 0; g < 3; ++g)
                #pragma unroll
                for (int u = 0; u < 2; ++u)
                    acc[g][u] = MFMA16x16x32(af[kt], wf[g][u][kt], acc[g][u]);
        #pragma unroll
        for (int g = 0; g < 3; ++g)
            #pragma unroll
            for (int u = 0; u < 2; ++u) {
                const float bi = b_ih[g*H + 32*w + 16*u + ln];
                #pragma unroll
                for (int rg = 0; rg < 4; ++rg)
                    gx[g][u][rg] = acc[g][u][rg] + bi;
            }
    }

    // ---- W_hh B-fragments + b_hh ----
    float bh[3][2];
    #pragma unroll
    for (int g = 0; g < 3; ++g)
        #pragma unroll
        for (int u = 0; u < 2; ++u) {
            const int crow = g*H + 32*w + 16*u + ln;
            bh[g][u] = b_hh[crow];
            #pragma unroll
            for (int kt = 0; kt < 4; ++kt)
                wf[g][u][kt] = load8_cvt(W_hh + (size_t)crow * H + kt*32 + lg*8);
        }

    const int lb0 = b0 - base;

    for (int t = 0; t < T_STEPS; ++t) {
        // A-frags from h(t-1)
        bf16x8 af[4];
        #pragma unroll
        for (int kt = 0; kt < 4; ++kt)
            af[kt] = *(const bf16x8*)&hbf[ln][kt*32 + lg*8];

        f32x4 ga[3][2];
        #pragma unroll
        for (int g = 0; g < 3; ++g)
            #pragma unroll
            for (int u = 0; u < 2; ++u) ga[g][u] = (f32x4)(0.f);
        #pragma unroll
        for (int kt = 0; kt < 4; ++kt)
            #pragma unroll
            for (int g = 0; g < 3; ++g)
                #pragma unroll
                for (int u = 0; u < 2; ++u)
                    ga[g][u] = MFMA16x16x32(af[kt], wf[g][u][kt], ga[g][u]);

        // gates: fully register-local (r/z/n of hidden unit j share lane+reg)
        unsigned short hb[2][4];
        #pragma unroll
        for (int u = 0; u < 2; ++u) {
            const int j = 32*w + 16*u + ln;
            #pragma unroll
            for (int rg = 0; rg < 4; ++rg) {
                const float rr = fast_sigm(gx[0][u][rg] + ga[0][u][rg] + bh[0][u]);
                const float zz = fast_sigm(gx[1][u][rg] + ga[1][u][rg] + bh[1][u]);
                const float nn = fast_tanh(gx[2][u][rg] + rr * (ga[2][u][rg] + bh[2][u]));
                const float h  = (1.f - zz) * nn + zz * h_reg[u][rg];
                h_reg[u][rg] = h;
                const unsigned short h16 = (unsigned short)f2b(h);
                hb[u][rg] = h16;
                const int r = lg*4 + rg;
                hist[(size_t)(lb0 + r) * (T_STEPS * H) + t * H + j] = h16;
            }
        }
        __syncthreads();   // all A-frag reads of h(t-1) complete
        #pragma unroll
        for (int u = 0; u < 2; ++u) {
            const int j = 32*w + 16*u + ln;
            #pragma unroll
            for (int rg = 0; rg < 4; ++rg)
                hbf[lg*4 + rg][j] = (short)hb[u][rg];
        }
        __syncthreads();   // h(t) visible for next step
    }
}

// ===========================================================================
// Kernel B: loc/scale heads as a batched GEMM over (b,t) rows.
// 256 thr = 4 waves; waves 0,1 = loc head (ch 0..127), waves 2,3 = sc head.
// 32 rows/block. LN + second linear via 16-lane shuffle + wave-pair LDS.
// ===========================================================================
__global__ __launch_bounds__(256, 2) void heads_kernel(
    const unsigned short* __restrict__ hist, int base,
    const float* __restrict__ loc1_w, const float* __restrict__ loc1_b,
    const float* __restrict__ loc_ln_g, const float* __restrict__ loc_ln_b,
    const float* __restrict__ loc2_w, const float* __restrict__ loc2_b,
    const float* __restrict__ sc1_w, const float* __restrict__ sc1_b,
    const float* __restrict__ sc_ln_g, const float* __restrict__ sc_ln_b,
    const float* __restrict__ sc2_w, const float* __restrict__ sc2_b,
    float* __restrict__ traj)
{
    __shared__ short habf[32][136];
    __shared__ float red[2][32][4];        // [head][row][s0,q0,s1,q1]
    __shared__ float red2[2][32][2][2];    // [head][row][pairwave][o]

    const int tid = threadIdx.x;
    const int w  = tid >> 6;
    const int l  = tid & 63;
    const int ln = l & 15;
    const int lg = l >> 4;
    const int head = w >> 1;               // 0 = loc, 1 = sc
    const int wp = w & 1;                  // channel half within head
    const int flat0 = blockIdx.x * 32;     // local flat row base (b_local*30 + t)

    const float* __restrict__ W1  = head ? sc1_w   : loc1_w;
    const float* __restrict__ B1v = head ? sc1_b   : loc1_b;
    const float* __restrict__ Gv  = head ? sc_ln_g : loc_ln_g;
    const float* __restrict__ Bv  = head ? sc_ln_b : loc_ln_b;
    const float* __restrict__ W2  = head ? sc2_w   : loc2_w;
    const float* __restrict__ B2v = head ? sc2_b   : loc2_b;

    bf16x8 wf[4][4];
    float bias1[4], lng[4], lnb[4], w2a[4], w2b[4];
    #pragma unroll
    for (int nt = 0; nt < 4; ++nt) {
        const int c = 64*wp + 16*nt + ln;
        #pragma unroll
        for (int kt = 0; kt < 4; ++kt)
            wf[nt][kt] = load8_cvt(W1 + (size_t)c * H + kt*32 + lg*8);
        bias1[nt] = B1v[c]; lng[nt] = Gv[c]; lnb[nt] = Bv[c];
        w2a[nt] = W2[c];    w2b[nt] = W2[H + c];
    }

    // stage 32 rows of bf16 h into padded LDS
    #pragma unroll
    for (int i = 0; i < 2; ++i) {
        const int c = tid + 256*i;
        const int r = c >> 4, seg = c & 15;
        const uint4 v = *(const uint4*)(hist + (size_t)(flat0 + r) * H + seg*8);
        *(uint4*)&habf[r][seg*8] = v;
    }
    __syncthreads();

    f32x4 acc[2][4];
    #pragma unroll
    for (int m = 0; m < 2; ++m) {
        #pragma unroll
        for (int nt = 0; nt < 4; ++nt) acc[m][nt] = (f32x4)(0.f);
        bf16x8 af[4];
        #pragma unroll
        for (int kt = 0; kt < 4; ++kt)
            af[kt] = *(const bf16x8*)&habf[m*16 + ln][kt*32 + lg*8];
        #pragma unroll
        for (int kt = 0; kt < 4; ++kt)
            #pragma unroll
            for (int nt = 0; nt < 4; ++nt)
                acc[m][nt] = MFMA16x16x32(af[kt], wf[nt][kt], acc[m][nt]);
    }

    // bias + LN stats (per-row partial over this wave's 64 channels)
    #pragma unroll
    for (int m = 0; m < 2; ++m)
        #pragma unroll
        for (int rg = 0; rg < 4; ++rg) {
            float s = 0.f, q = 0.f;
            #pragma unroll
            for (int nt = 0; nt < 4; ++nt) {
                const float a = acc[m][nt][rg] + bias1[nt];
                acc[m][nt][rg] = a;
                s += a; q += a*a;
            }
            #pragma unroll
            for (int off = 1; off < 16; off <<= 1) {
                s += __shfl_xor(s, off);
                q += __shfl_xor(q, off);
            }
            if (ln == 0) {
                const int row = m*16 + lg*4 + rg;
                red[head][row][wp*2+0] = s;
                red[head][row][wp*2+1] = q;
            }
        }
    __syncthreads();

    // LN + relu + second-linear partials
    #pragma unroll
    for (int m = 0; m < 2; ++m)
        #pragma unroll
        for (int rg = 0; rg < 4; ++rg) {
            const int row = m*16 + lg*4 + rg;
            const float4 rv = *(const float4*)&red[head][row][0];
            const float S = rv.x + rv.z, Q = rv.y + rv.w;
            const float mu = S * (1.f/H);
            const float var = Q * (1.f/H) - mu*mu;
            const float rs = rsqrtf(var + LN_EPS);
            float p0 = 0.f, p1 = 0.f;
            #pragma unroll
            for (int nt = 0; nt < 4; ++nt) {
                float v = (acc[m][nt][rg] - mu) * rs * lng[nt] + lnb[nt];
                v = fmaxf(v, 0.f);
                p0 += v * w2a[nt];
                p1 += v * w2b[nt];
            }
            #pragma unroll
            for (int off = 1; off < 16; off <<= 1) {
                p0 += __shfl_xor(p0, off);
                p1 += __shfl_xor(p1, off);
            }
            if (ln == 0) {
                red2[head][row][wp][0] = p0;
                red2[head][row][wp][1] = p1;
            }
        }
    __syncthreads();

    // combine wave pair, ELU for scale head, store
    if (wp == 0 && ln == 0) {
        #pragma unroll
        for (int m = 0; m < 2; ++m)
            #pragma unroll
            for (int rg = 0; rg < 4; ++rg) {
                const int row = m*16 + lg*4 + rg;
                const int flat = flat0 + row;
                const int lb = flat / T_STEPS;
                const int t = flat - lb * T_STEPS;
                const int b = base + lb;
                #pragma unroll
                for (int o = 0; o < 2; ++o) {
                    float val = red2[head][row][0][o] + red2[head][row][1][o] + B2v[o];
                    if (head) val = (val > 0.f ? val : expm1f(val)) + 1.0f + MIN_SCALE;
                    traj[((size_t)b * T_STEPS + t) * 4 + head*2 + o] = val;
                }
            }
    }
}

// ===========================================================================
// pi head (unchanged fp32 baseline this round)
// ===========================================================================
__global__ __launch_bounds__(512) void pi_kernel(
    const float* __restrict__ local_embed,
    const float* __restrict__ global_embed,
    const float* __restrict__ pi1_w,
    const float* __restrict__ pi1_b,
    const float* __restrict__ ln1_g, const float* __restrict__ ln1_b,
    const float* __restrict__ pi2_w,
    const float* __restrict__ pi2_b,
    const float* __restrict__ ln2_g, const float* __restrict__ ln2_b,
    const float* __restrict__ pi3_w,
    const float* __restrict__ pi3_b,
    float* __restrict__ pi_out)
{
    __shared__ float inbuf[4][2 * H];
    __shared__ float h1[4][H];
    __shared__ float red[4][2][2];

    const int g = threadIdx.x >> 7;
    const int j = threadIdx.x & (H - 1);
    const int w = (threadIdx.x >> 6) & 1;
    const int lane = threadIdx.x & 63;
    const int b = blockIdx.x * 4 + g;
    const int n = b & (N_AG - 1);
    const int m = b >> 13;

    inbuf[g][j]     = local_embed[(size_t)n * H + j];
    inbuf[g][H + j] = global_embed[(size_t)b * I_DIM + j];
    __syncthreads();

    float acc = pi1_b[j];
    {
        const float4* w4 = (const float4*)(pi1_w + (size_t)j * 2 * H);
        const float4* in4 = (const float4*)(&inbuf[g][0]);
        #pragma unroll 4
        for (int k4 = 0; k4 < 2 * H / 4; ++k4) acc += dot4(w4[k4], in4[k4]);
    }
    {
        const float s = wave_sum(acc);
        const float q = wave_sum(acc * acc);
        if (lane == 0) { red[g][w][0] = s; red[g][w][1] = q; }
    }
    __syncthreads();
    {
        const float s = red[g][0][0] + red[g][1][0];
        const float q = red[g][0][1] + red[g][1][1];
        const float mu = s * (1.f / H);
        const float var = q * (1.f / H) - mu * mu;
        h1[g][j] = fmaxf((acc - mu) * rsqrtf(var + LN_EPS) * ln1_g[j] + ln1_b[j], 0.f);
    }
    __syncthreads();

    float acc2 = pi2_b[j];
    {
        const float4* w4 = (const float4*)(pi2_w + (size_t)j * H);
        const float4* h4 = (const float4*)(&h1[g][0]);
        #pragma unroll 4
        for (int k4 = 0; k4 < H / 4; ++k4) acc2 += dot4(w4[k4], h4[k4]);
    }
    {
        const float s = wave_sum(acc2);
        const float q = wave_sum(acc2 * acc2);
        if (lane == 0) { red[g][w][0] = s; red[g][w][1] = q; }
    }
    __syncthreads();
    float v2;
    {
        const float s = red[g][0][0] + red[g][1][0];
        const float q = red[g][0][1] + red[g][1][1];
        const float mu = s * (1.f / H);
        const float var = q * (1.f / H) - mu * mu;
        v2 = fmaxf((acc2 - mu) * rsqrtf(var + LN_EPS) * ln2_g[j] + ln2_b[j], 0.f);
    }

    const float part = wave_sum(v2 * pi3_w[j]);
    __syncthreads();
    if (lane == 0) red[g][w][0] = part;
    __syncthreads();
    if (j == 0) pi_out[(size_t)n * M_MODES + m] = red[g][0][0] + red[g][1][0] + pi3_b[0];
}

// ===========================================================================
// Fallback (round-1 fused fp32 kernel) — used only if ws_size is tiny.
// ===========================================================================
__global__ __launch_bounds__(128) void gru_heads_kernel(
    const float* __restrict__ local_embed,
    const float* __restrict__ global_embed,
    const float* __restrict__ W_ih,
    const float* __restrict__ W_hh,
    const float* __restrict__ b_ih,
    const float* __restrict__ b_hh,
    const float* __restrict__ loc1_w,
    const float* __restrict__ loc1_b,
    const float* __restrict__ loc_ln_g, const float* __restrict__ loc_ln_b,
    const float* __restrict__ loc2_w,
    const float* __restrict__ loc2_b,
    const float* __restrict__ sc1_w, const float* __restrict__ sc1_b,
    const float* __restrict__ sc_ln_g, const float* __restrict__ sc_ln_b,
    const float* __restrict__ sc2_w, const float* __restrict__ sc2_b,
    float* __restrict__ traj)
{
    __shared__ float hA[ROWS][H];
    __shared__ float hB[ROWS][H];
    __shared__ float lnbuf[ROWS][2][H];
    __shared__ float red[2][ROWS][2][2];

    const int j    = threadIdx.x;
    const int wid  = j >> 6;
    const int lane = j & 63;
    const int b0   = blockIdx.x * ROWS;

    #pragma unroll
    for (int r = 0; r < ROWS; ++r) {
        const int b = b0 + r;
        const int n = b & (N_AG - 1);
        hA[r][j] = local_embed[(size_t)n * H + j];
        lnbuf[r][0][j] = global_embed[(size_t)b * I_DIM + j];
    }
    __syncthreads();

    const float bhr = b_hh[j], bhz = b_hh[H + j], bhn = b_hh[2 * H + j];
    const float lgj = loc_ln_g[j], lbj = loc_ln_b[j];
    const float sgj = sc_ln_g[j],  sbj = sc_ln_b[j];
    const float l1b = loc1_b[j],   s1b = sc1_b[j];

    float gx0[ROWS], gx1[ROWS], gx2[ROWS];
    #pragma unroll
    for (int r = 0; r < ROWS; ++r) { gx0[r] = 0.f; gx1[r] = 0.f; gx2[r] = 0.f; }
    {
        const float4* u0 = (const float4*)(W_ih + (size_t)j * I_DIM);
        const float4* u1 = (const float4*)(W_ih + (size_t)(H + j) * I_DIM);
        const float4* u2 = (const float4*)(W_ih + (size_t)(2 * H + j) * I_DIM);
        #pragma unroll 4
        for (int k4 = 0; k4 < I_DIM / 4; ++k4) {
            const float4 w0 = u0[k4], w1 = u1[k4], w2 = u2[k4];
            #pragma unroll
            for (int r = 0; r < ROWS; ++r) {
                const float4 xv = ((const float4*)(&lnbuf[r][0][0]))[k4];
                gx0[r] += dot4(w0, xv);
                gx1[r] += dot4(w1, xv);
                gx2[r] += dot4(w2, xv);
            }
        }
        const float bi0 = b_ih[j], bi1 = b_ih[H + j], bi2 = b_ih[2 * H + j];
        #pragma unroll
        for (int r = 0; r < ROWS; ++r) { gx0[r] += bi0; gx1[r] += bi1; gx2[r] += bi2; }
    }

    const float4* w0p = (const float4*)(W_hh + (size_t)j * H);
    const float4* w1p = (const float4*)(W_hh + (size_t)(H + j) * H);
    const float4* w2p = (const float4*)(W_hh + (size_t)(2 * H + j) * H);
    const float4* wlp = (const float4*)(loc1_w + (size_t)j * H);
    const float4* wsp = (const float4*)(sc1_w + (size_t)j * H);

    for (int t = 0; t < T_STEPS; ++t) {
        float* hc = (t & 1) ? &hB[0][0] : &hA[0][0];
        float* hn = (t & 1) ? &hA[0][0] : &hB[0][0];

        float ar[ROWS], az[ROWS], an[ROWS];
        #pragma unroll
        for (int r = 0; r < ROWS; ++r) { ar[r] = 0.f; az[r] = 0.f; an[r] = 0.f; }
        #pragma unroll 4
        for (int k4 = 0; k4 < H / 4; ++k4) {
            const float4 w0 = w0p[k4], w1 = w1p[k4], w2 = w2p[k4];
            #pragma unroll
            for (int r = 0; r < ROWS; ++r) {
                const float4 hv = ((const float4*)(hc + r * H))[k4];
                ar[r] += dot4(w0, hv);
                az[r] += dot4(w1, hv);
                an[r] += dot4(w2, hv);
            }
        }

        #pragma unroll
        for (int r = 0; r < ROWS; ++r) {
            const float rr = sigm(gx0[r] + ar[r] + bhr);
            const float zz = sigm(gx1[r] + az[r] + bhz);
            const float nn = tanhf(gx2[r] + rr * (an[r] + bhn));
            const float hold = hc[r * H + j];
            hn[r * H + j] = (1.f - zz) * nn + zz * hold;
        }
        __syncthreads();

        float aL[ROWS], aS[ROWS];
        #pragma unroll
        for (int r = 0; r < ROWS; ++r) { aL[r] = l1b; aS[r] = s1b; }
        #pragma unroll 4
        for (int k4 = 0; k4 < H / 4; ++k4) {
            const float4 wl = wlp[k4], ws = wsp[k4];
            #pragma unroll
            for (int r = 0; r < ROWS; ++r) {
                const float4 hv = ((const float4*)(hn + r * H))[k4];
                aL[r] += dot4(wl, hv);
                aS[r] += dot4(ws, hv);
            }
        }

        #pragma unroll
        for (int r = 0; r < ROWS; ++r) {
            const float sL = wave_sum(aL[r]);
            const float qL = wave_sum(aL[r] * aL[r]);
            const float sS = wave_sum(aS[r]);
            const float qS = wave_sum(aS[r] * aS[r]);
            if (lane == 0) {
                red[wid][r][0][0] = sL; red[wid][r][0][1] = qL;
                red[wid][r][1][0] = sS; red[wid][r][1][1] = qS;
            }
        }
        __syncthreads();

        #pragma unroll
        for (int r = 0; r < ROWS; ++r) {
            const float sL = red[0][r][0][0] + red[1][r][0][0];
            const float qL = red[0][r][0][1] + red[1][r][0][1];
            const float mL = sL * (1.f / H);
            const float vL = qL * (1.f / H) - mL * mL;
            lnbuf[r][0][j] = fmaxf((aL[r] - mL) * rsqrtf(vL + LN_EPS) * lgj + lbj, 0.f);
            const float sS = red[0][r][1][0] + red[1][r][1][0];
            const float qS = red[0][r][1][1] + red[1][r][1][1];
            const float mS = sS * (1.f / H);
            const float vS = qS * (1.f / H) - mS * mS;
            lnbuf[r][1][j] = fmaxf((aS[r] - mS) * rsqrtf(vS + LN_EPS) * sgj + sbj, 0.f);
        }
        __syncthreads();

        if (threadIdx.x < ROWS * 4) {
            const int r = threadIdx.x >> 2;
            const int o = threadIdx.x & 3;
            const int head = (o >> 1);
            const int oo = o & 1;
            const float* w = head ? (sc2_w + oo * H) : (loc2_w + oo * H);
            const float4* w4 = (const float4*)w;
            const float4* v4 = (const float4*)(&lnbuf[r][head][0]);
            float acc = 0.f;
            #pragma unroll
            for (int k4 = 0; k4 < H / 4; ++k4) acc += dot4(w4[k4], v4[k4]);
            acc += head ? sc2_b[oo] : loc2_b[oo];
            if (head) {
                acc = (acc > 0.f ? acc : expm1f(acc)) + 1.0f + MIN_SCALE;
            }
            traj[((size_t)(b0 + r) * T_STEPS + t) * 4 + o] = acc;
        }
    }
}

extern "C" void kernel_launch(void* const* d_in, const int* in_sizes, int n_in,
                              void* d_out, int out_size, void* d_ws, size_t ws_size,
                              hipStream_t stream) {
    (void)in_sizes; (void)n_in; (void)out_size;
    const float* local_embed  = (const float*)d_in[0];
    const float* global_embed = (const float*)d_in[1];
    const float* W_ih   = (const float*)d_in[2];
    const float* W_hh   = (const float*)d_in[3];
    const float* b_ih   = (const float*)d_in[4];
    const float* b_hh   = (const float*)d_in[5];
    const float* loc1_w = (const float*)d_in[6];
    const float* loc1_b = (const float*)d_in[7];
    const float* loc_ln_g = (const float*)d_in[8];
    const float* loc_ln_b = (const float*)d_in[9];
    const float* loc2_w = (const float*)d_in[10];
    const float* loc2_b = (const float*)d_in[11];
    const float* sc1_w  = (const float*)d_in[12];
    const float* sc1_b  = (const float*)d_in[13];
    const float* sc_ln_g = (const float*)d_in[14];
    const float* sc_ln_b = (const float*)d_in[15];
    const float* sc2_w  = (const float*)d_in[16];
    const float* sc2_b  = (const float*)d_in[17];
    const float* pi1_w  = (const float*)d_in[18];
    const float* pi1_b  = (const float*)d_in[19];
    const float* pi_ln1_g = (const float*)d_in[20];
    const float* pi_ln1_b = (const float*)d_in[21];
    const float* pi2_w  = (const float*)d_in[22];
    const float* pi2_b  = (const float*)d_in[23];
    const float* pi_ln2_g = (const float*)d_in[24];
    const float* pi_ln2_b = (const float*)d_in[25];
    const float* pi3_w  = (const float*)d_in[26];
    const float* pi3_b  = (const float*)d_in[27];

    float* traj = (float*)d_out;
    float* pi_out = traj + (size_t)B_TOT * T_STEPS * 4;

    pi_kernel<<<B_TOT / 4, 512, 0, stream>>>(
        local_embed, global_embed, pi1_w, pi1_b, pi_ln1_g, pi_ln1_b,
        pi2_w, pi2_b, pi_ln2_g, pi_ln2_b, pi3_w, pi3_b, pi_out);

    // h-history (bf16) chunking against workspace size
    const size_t row_bytes = (size_t)T_STEPS * H * sizeof(unsigned short);  // 7680
    long long rc = (long long)(ws_size / row_bytes);
    int Rc = rc > B_TOT ? B_TOT : (int)rc;
    Rc &= ~15;

    if (Rc >= 16) {
        for (int basep = 0; basep < B_TOT; basep += Rc) {
            const int rows = (B_TOT - basep < Rc) ? (B_TOT - basep) : Rc;
            gru_rec_kernel<<<rows / 16, 256, 0, stream>>>(
                local_embed, global_embed, W_ih, W_hh, b_ih, b_hh,
                basep, (unsigned short*)d_ws);
            heads_kernel<<<(rows * T_STEPS) / 32, 256, 0, stream>>>(
                (const unsigned short*)d_ws, basep,
                loc1_w, loc1_b, loc_ln_g, loc_ln_b, loc2_w, loc2_b,
                sc1_w, sc1_b, sc_ln_g, sc_ln_b, sc2_w, sc2_b, traj);
        }
    } else {
        gru_heads_kernel<<<B_TOT / ROWS, 128, 0, stream>>>(
            local_embed, global_embed, W_ih, W_hh, b_ih, b_hh,
            loc1_w, loc1_b, loc_ln_g, loc_ln_b, loc2_w, loc2_b,
            sc1_w, sc1_b, sc_ln_g, sc_ln_b, sc2_w, sc2_b, traj);
    }
}

// Round 3
// 1102.626 us; speedup vs baseline: 6.6596x; 1.9021x over previous
//
#include <hip/hip_runtime.h>
#include <math.h>

#define H 128
#define I_DIM 128
#define T_STEPS 30
#define M_MODES 6
#define N_AG 8192
#define B_TOT (M_MODES * N_AG)   /* 49152 */
#define ROWS 16
#define LN_EPS 1e-5f
#define MIN_SCALE 0.001f

typedef short bf16x8 __attribute__((ext_vector_type(8)));
typedef float f32x4 __attribute__((ext_vector_type(4)));

#define MFMA16x16x32(A, B, C) __builtin_amdgcn_mfma_f32_16x16x32_bf16(A, B, C, 0, 0, 0)

__device__ __forceinline__ short f2b(float f) {
    union { float f; unsigned u; } v; v.f = f;
    return (short)((v.u + 0x7FFFu + ((v.u >> 16) & 1u)) >> 16);
}

__device__ __forceinline__ bf16x8 load8_cvt(const float* __restrict__ p) {
    const float4 a = ((const float4*)p)[0];
    const float4 b = ((const float4*)p)[1];
    bf16x8 r;
    r[0]=f2b(a.x); r[1]=f2b(a.y); r[2]=f2b(a.z); r[3]=f2b(a.w);
    r[4]=f2b(b.x); r[5]=f2b(b.y); r[6]=f2b(b.z); r[7]=f2b(b.w);
    return r;
}

__device__ __forceinline__ float fast_sigm(float x) {
    return __builtin_amdgcn_rcpf(1.f + __expf(-x));
}
__device__ __forceinline__ float fast_tanh(float x) {
    return 1.f - 2.f * __builtin_amdgcn_rcpf(1.f + __expf(2.f * x));
}

__device__ __forceinline__ float dot4(float4 a, float4 b) {
    return a.x * b.x + a.y * b.y + a.z * b.z + a.w * b.w;
}

__device__ __forceinline__ float wave_sum(float v) {
    #pragma unroll
    for (int off = 32; off > 0; off >>= 1) v += __shfl_xor(v, off);
    return v;
}

__device__ __forceinline__ float sigm(float x) {
    return 1.0f / (1.0f + expf(-x));
}

// ===========================================================================
// Kernel A: GRU recurrence via MFMA. 256 thr = 4 waves, 16 rows/block.
// Wave w owns hidden channels [32w,32w+32) of all 3 gates -> gate math is
// register-local in the MFMA D-layout. Emits bf16 h-history to `hist`
// via LDS-staged coalesced 16B stores.
// ===========================================================================
__global__ __launch_bounds__(256, 2) void gru_rec_kernel(
    const float* __restrict__ local_embed, const float* __restrict__ global_embed,
    const float* __restrict__ W_ih, const float* __restrict__ W_hh,
    const float* __restrict__ b_ih, const float* __restrict__ b_hh,
    int base, unsigned short* __restrict__ hist)
{
    __shared__ short xbuf[16][136];   // padded: row stride 272 B
    __shared__ short hbf[16][136];

    const int tid = threadIdx.x;
    const int w  = tid >> 6;          // wave 0..3
    const int l  = tid & 63;
    const int ln = l & 15;            // lane-in-16 (D col / A row / B col)
    const int lg = l >> 4;            // lane group (D row group / A,B k group)
    const int b0 = base + blockIdx.x * 16;

    // ---- stage x (bf16) and h0 (fp32 regs + bf16 LDS) ----
    float h_reg[2][4];
    #pragma unroll
    for (int u = 0; u < 2; ++u) {
        const int j = 32*w + 16*u + ln;
        #pragma unroll
        for (int rg = 0; rg < 4; ++rg) {
            const int r = lg*4 + rg;
            const int b = b0 + r;
            const int n = b & (N_AG - 1);
            xbuf[r][j] = f2b(global_embed[(size_t)b * I_DIM + j]);
            const float h0 = local_embed[(size_t)n * H + j];
            h_reg[u][rg] = h0;
            hbf[r][j] = f2b(h0);
        }
    }

    // ---- W_ih B-fragments (temporary; overwritten by W_hh below) ----
    bf16x8 wf[3][2][4];
    #pragma unroll
    for (int g = 0; g < 3; ++g)
        #pragma unroll
        for (int u = 0; u < 2; ++u) {
            const int crow = g*H + 32*w + 16*u + ln;
            #pragma unroll
            for (int kt = 0; kt < 4; ++kt)
                wf[g][u][kt] = load8_cvt(W_ih + (size_t)crow * I_DIM + kt*32 + lg*8);
        }

    __syncthreads();

    // ---- gx = x @ W_ih^T + b_ih (once; same input every timestep) ----
    float gx[3][2][4];
    {
        bf16x8 af[4];
        #pragma unroll
        for (int kt = 0; kt < 4; ++kt)
            af[kt] = *(const bf16x8*)&xbuf[ln][kt*32 + lg*8];
        f32x4 acc[3][2];
        #pragma unroll
        for (int g = 0; g < 3; ++g)
            #pragma unroll
            for (int u = 0; u < 2; ++u)
                acc[g][u] = (f32x4)(0.f);
        #pragma unroll
        for (int kt = 0; kt < 4; ++kt)
            #pragma unroll
            for (int g = 0; g < 3; ++g)
                #pragma unroll
                for (int u = 0; u < 2; ++u)
                    acc[g][u] = MFMA16x16x32(af[kt], wf[g][u][kt], acc[g][u]);
        #pragma unroll
        for (int g = 0; g < 3; ++g)
            #pragma unroll
            for (int u = 0; u < 2; ++u) {
                const float bi = b_ih[g*H + 32*w + 16*u + ln];
                #pragma unroll
                for (int rg = 0; rg < 4; ++rg)
                    gx[g][u][rg] = acc[g][u][rg] + bi;
            }
    }

    // ---- W_hh B-fragments + b_hh ----
    float bh[3][2];
    #pragma unroll
    for (int g = 0; g < 3; ++g)
        #pragma unroll
        for (int u = 0; u < 2; ++u) {
            const int crow = g*H + 32*w + 16*u + ln;
            bh[g][u] = b_hh[crow];
            #pragma unroll
            for (int kt = 0; kt < 4; ++kt)
                wf[g][u][kt] = load8_cvt(W_hh + (size_t)crow * H + kt*32 + lg*8);
        }

    const int lb0 = b0 - base;
    const int sr  = tid >> 4;          // store row 0..15
    const int seg = tid & 15;          // store segment 0..15 (8 shorts each)

    for (int t = 0; t < T_STEPS; ++t) {
        // A-frags from h(t-1)
        bf16x8 af[4];
        #pragma unroll
        for (int kt = 0; kt < 4; ++kt)
            af[kt] = *(const bf16x8*)&hbf[ln][kt*32 + lg*8];

        f32x4 ga[3][2];
        #pragma unroll
        for (int g = 0; g < 3; ++g)
            #pragma unroll
            for (int u = 0; u < 2; ++u) ga[g][u] = (f32x4)(0.f);
        #pragma unroll
        for (int kt = 0; kt < 4; ++kt)
            #pragma unroll
            for (int g = 0; g < 3; ++g)
                #pragma unroll
                for (int u = 0; u < 2; ++u)
                    ga[g][u] = MFMA16x16x32(af[kt], wf[g][u][kt], ga[g][u]);

        // gates: fully register-local (r/z/n of hidden unit j share lane+reg)
        unsigned short hb[2][4];
        #pragma unroll
        for (int u = 0; u < 2; ++u) {
            #pragma unroll
            for (int rg = 0; rg < 4; ++rg) {
                const float rr = fast_sigm(gx[0][u][rg] + ga[0][u][rg] + bh[0][u]);
                const float zz = fast_sigm(gx[1][u][rg] + ga[1][u][rg] + bh[1][u]);
                const float nn = fast_tanh(gx[2][u][rg] + rr * (ga[2][u][rg] + bh[2][u]));
                const float h  = (1.f - zz) * nn + zz * h_reg[u][rg];
                h_reg[u][rg] = h;
                hb[u][rg] = (unsigned short)f2b(h);
            }
        }
        __syncthreads();   // all A-frag reads of h(t-1) complete
        #pragma unroll
        for (int u = 0; u < 2; ++u) {
            const int j = 32*w + 16*u + ln;
            #pragma unroll
            for (int rg = 0; rg < 4; ++rg)
                hbf[lg*4 + rg][j] = (short)hb[u][rg];
        }
        __syncthreads();   // h(t) visible for next step + for store

        // coalesced history store: one uint4 per thread, 256B/row contiguous
        const uint4 hv = *(const uint4*)&hbf[sr][seg*8];
        *(uint4*)(hist + (size_t)(lb0 + sr) * (T_STEPS * H) + t * H + seg*8) = hv;
    }
}

// ===========================================================================
// Kernel B: loc/scale heads as a batched GEMM over (b,t) rows.
// 256 thr = 4 waves; waves 0,1 = loc head, waves 2,3 = sc head.
// ===========================================================================
__global__ __launch_bounds__(256, 2) void heads_kernel(
    const unsigned short* __restrict__ hist, int base,
    const float* __restrict__ loc1_w, const float* __restrict__ loc1_b,
    const float* __restrict__ loc_ln_g, const float* __restrict__ loc_ln_b,
    const float* __restrict__ loc2_w, const float* __restrict__ loc2_b,
    const float* __restrict__ sc1_w, const float* __restrict__ sc1_b,
    const float* __restrict__ sc_ln_g, const float* __restrict__ sc_ln_b,
    const float* __restrict__ sc2_w, const float* __restrict__ sc2_b,
    float* __restrict__ traj)
{
    __shared__ short habf[32][136];
    __shared__ float red[2][32][4];        // [head][row][s0,q0,s1,q1]
    __shared__ float red2[2][32][2][2];    // [head][row][pairwave][o]

    const int tid = threadIdx.x;
    const int w  = tid >> 6;
    const int l  = tid & 63;
    const int ln = l & 15;
    const int lg = l >> 4;
    const int head = w >> 1;               // 0 = loc, 1 = sc
    const int wp = w & 1;                  // channel half within head
    const int flat0 = blockIdx.x * 32;     // local flat row base (b_local*30 + t)

    const float* __restrict__ W1  = head ? sc1_w   : loc1_w;
    const float* __restrict__ B1v = head ? sc1_b   : loc1_b;
    const float* __restrict__ Gv  = head ? sc_ln_g : loc_ln_g;
    const float* __restrict__ Bv  = head ? sc_ln_b : loc_ln_b;
    const float* __restrict__ W2  = head ? sc2_w   : loc2_w;
    const float* __restrict__ B2v = head ? sc2_b   : loc2_b;

    bf16x8 wf[4][4];
    float bias1[4], lng[4], lnb[4], w2a[4], w2b[4];
    #pragma unroll
    for (int nt = 0; nt < 4; ++nt) {
        const int c = 64*wp + 16*nt + ln;
        #pragma unroll
        for (int kt = 0; kt < 4; ++kt)
            wf[nt][kt] = load8_cvt(W1 + (size_t)c * H + kt*32 + lg*8);
        bias1[nt] = B1v[c]; lng[nt] = Gv[c]; lnb[nt] = Bv[c];
        w2a[nt] = W2[c];    w2b[nt] = W2[H + c];
    }

    // stage 32 rows of bf16 h into padded LDS
    #pragma unroll
    for (int i = 0; i < 2; ++i) {
        const int c = tid + 256*i;
        const int r = c >> 4, seg = c & 15;
        const uint4 v = *(const uint4*)(hist + (size_t)(flat0 + r) * H + seg*8);
        *(uint4*)&habf[r][seg*8] = v;
    }
    __syncthreads();

    f32x4 acc[2][4];
    #pragma unroll
    for (int m = 0; m < 2; ++m) {
        #pragma unroll
        for (int nt = 0; nt < 4; ++nt) acc[m][nt] = (f32x4)(0.f);
        bf16x8 af[4];
        #pragma unroll
        for (int kt = 0; kt < 4; ++kt)
            af[kt] = *(const bf16x8*)&habf[m*16 + ln][kt*32 + lg*8];
        #pragma unroll
        for (int kt = 0; kt < 4; ++kt)
            #pragma unroll
            for (int nt = 0; nt < 4; ++nt)
                acc[m][nt] = MFMA16x16x32(af[kt], wf[nt][kt], acc[m][nt]);
    }

    // bias + LN stats (per-row partial over this wave's 64 channels)
    #pragma unroll
    for (int m = 0; m < 2; ++m)
        #pragma unroll
        for (int rg = 0; rg < 4; ++rg) {
            float s = 0.f, q = 0.f;
            #pragma unroll
            for (int nt = 0; nt < 4; ++nt) {
                const float a = acc[m][nt][rg] + bias1[nt];
                acc[m][nt][rg] = a;
                s += a; q += a*a;
            }
            #pragma unroll
            for (int off = 1; off < 16; off <<= 1) {
                s += __shfl_xor(s, off);
                q += __shfl_xor(q, off);
            }
            if (ln == 0) {
                const int row = m*16 + lg*4 + rg;
                red[head][row][wp*2+0] = s;
                red[head][row][wp*2+1] = q;
            }
        }
    __syncthreads();

    // LN + relu + second-linear partials
    #pragma unroll
    for (int m = 0; m < 2; ++m)
        #pragma unroll
        for (int rg = 0; rg < 4; ++rg) {
            const int row = m*16 + lg*4 + rg;
            const float4 rv = *(const float4*)&red[head][row][0];
            const float S = rv.x + rv.z, Q = rv.y + rv.w;
            const float mu = S * (1.f/H);
            const float var = Q * (1.f/H) - mu*mu;
            const float rs = rsqrtf(var + LN_EPS);
            float p0 = 0.f, p1 = 0.f;
            #pragma unroll
            for (int nt = 0; nt < 4; ++nt) {
                float v = (acc[m][nt][rg] - mu) * rs * lng[nt] + lnb[nt];
                v = fmaxf(v, 0.f);
                p0 += v * w2a[nt];
                p1 += v * w2b[nt];
            }
            #pragma unroll
            for (int off = 1; off < 16; off <<= 1) {
                p0 += __shfl_xor(p0, off);
                p1 += __shfl_xor(p1, off);
            }
            if (ln == 0) {
                red2[head][row][wp][0] = p0;
                red2[head][row][wp][1] = p1;
            }
        }
    __syncthreads();

    // combine wave pair, ELU for scale head, store
    if (wp == 0 && ln == 0) {
        #pragma unroll
        for (int m = 0; m < 2; ++m)
            #pragma unroll
            for (int rg = 0; rg < 4; ++rg) {
                const int row = m*16 + lg*4 + rg;
                const int flat = flat0 + row;
                const int lb = flat / T_STEPS;
                const int t = flat - lb * T_STEPS;
                const int b = base + lb;
                #pragma unroll
                for (int o = 0; o < 2; ++o) {
                    float val = red2[head][row][0][o] + red2[head][row][1][o] + B2v[o];
                    if (head) val = (val > 0.f ? val : expm1f(val)) + 1.0f + MIN_SCALE;
                    traj[((size_t)b * T_STEPS + t) * 4 + head*2 + o] = val;
                }
            }
    }
}

// ===========================================================================
// Kernel C: pi head via MFMA. 32 rows/block, 256 thr = 4 waves.
// Wave w owns output cols [32w, 32w+32) for layers 1 and 2.
// ===========================================================================
__global__ __launch_bounds__(256, 2) void pi_mfma_kernel(
    const float* __restrict__ local_embed, const float* __restrict__ global_embed,
    const float* __restrict__ pi1_w, const float* __restrict__ pi1_b,
    const float* __restrict__ ln1_g, const float* __restrict__ ln1_b,
    const float* __restrict__ pi2_w, const float* __restrict__ pi2_b,
    const float* __restrict__ ln2_g, const float* __restrict__ ln2_b,
    const float* __restrict__ pi3_w, const float* __restrict__ pi3_b,
    float* __restrict__ pi_out)
{
    __shared__ short inbf[32][264];        // 32 rows x 256 cols, stride 528B
    __shared__ short h1bf[32][136];        // 32 rows x 128 cols, stride 272B
    __shared__ float redL[4][32][2];       // [wave][row][s,q]
    __shared__ float red3[4][32];

    const int tid = threadIdx.x;
    const int w  = tid >> 6;
    const int l  = tid & 63;
    const int ln = l & 15;
    const int lg = l >> 4;
    const int r0 = blockIdx.x * 32;

    // ---- stage 32 input rows [local(128) | global(128)] as bf16 ----
    {
        const int r   = tid >> 3;          // 0..31
        const int seg = tid & 7;           // 0..7, 32 cols each
        const int b = r0 + r;
        const int n = b & (N_AG - 1);
        const float* src = (seg < 4) ? (local_embed + (size_t)n * H + seg * 32)
                                     : (global_embed + (size_t)b * I_DIM + (seg - 4) * 32);
        short tmp[32];
        #pragma unroll
        for (int i = 0; i < 8; ++i) {
            const float4 v = ((const float4*)src)[i];
            tmp[i*4+0]=f2b(v.x); tmp[i*4+1]=f2b(v.y); tmp[i*4+2]=f2b(v.z); tmp[i*4+3]=f2b(v.w);
        }
        #pragma unroll
        for (int i = 0; i < 4; ++i)
            *(uint4*)&inbf[r][seg*32 + i*8] = *(uint4*)&tmp[i*8];
    }

    // ---- per-wave column params + weight fragments ----
    bf16x8 wf1[2][8];
    bf16x8 wf2[2][4];
    float b1[2], g1[2], bb1[2], b2[2], g2[2], bb2[2], w3[2];
    #pragma unroll
    for (int nt = 0; nt < 2; ++nt) {
        const int c = 32*w + 16*nt + ln;
        #pragma unroll
        for (int kt = 0; kt < 8; ++kt)
            wf1[nt][kt] = load8_cvt(pi1_w + (size_t)c * (2*H) + kt*32 + lg*8);
        #pragma unroll
        for (int kt = 0; kt < 4; ++kt)
            wf2[nt][kt] = load8_cvt(pi2_w + (size_t)c * H + kt*32 + lg*8);
        b1[nt] = pi1_b[c]; g1[nt] = ln1_g[c]; bb1[nt] = ln1_b[c];
        b2[nt] = pi2_b[c]; g2[nt] = ln2_g[c]; bb2[nt] = ln2_b[c];
        w3[nt] = pi3_w[c];
    }
    __syncthreads();

    // ---- layer 1: [32,256] @ [256->cols] ----
    f32x4 acc1[2][2];
    #pragma unroll
    for (int m = 0; m < 2; ++m) {
        #pragma unroll
        for (int nt = 0; nt < 2; ++nt) acc1[m][nt] = (f32x4)(0.f);
        bf16x8 af[8];
        #pragma unroll
        for (int kt = 0; kt < 8; ++kt)
            af[kt] = *(const bf16x8*)&inbf[m*16 + ln][kt*32 + lg*8];
        #pragma unroll
        for (int kt = 0; kt < 8; ++kt)
            #pragma unroll
            for (int nt = 0; nt < 2; ++nt)
                acc1[m][nt] = MFMA16x16x32(af[kt], wf1[nt][kt], acc1[m][nt]);
    }

    // LN1 stats: per-wave partial over its 32 cols
    #pragma unroll
    for (int m = 0; m < 2; ++m)
        #pragma unroll
        for (int rg = 0; rg < 4; ++rg) {
            float s = 0.f, q = 0.f;
            #pragma unroll
            for (int nt = 0; nt < 2; ++nt) {
                const float a = acc1[m][nt][rg] + b1[nt];
                acc1[m][nt][rg] = a;
                s += a; q += a*a;
            }
            #pragma unroll
            for (int off = 1; off < 16; off <<= 1) {
                s += __shfl_xor(s, off);
                q += __shfl_xor(q, off);
            }
            if (ln == 0) {
                const int row = m*16 + lg*4 + rg;
                redL[w][row][0] = s;
                redL[w][row][1] = q;
            }
        }
    __syncthreads();

    // apply LN1 + relu -> h1bf
    #pragma unroll
    for (int m = 0; m < 2; ++m)
        #pragma unroll
        for (int rg = 0; rg < 4; ++rg) {
            const int row = m*16 + lg*4 + rg;
            const float S = redL[0][row][0] + redL[1][row][0] + redL[2][row][0] + redL[3][row][0];
            const float Q = redL[0][row][1] + redL[1][row][1] + redL[2][row][1] + redL[3][row][1];
            const float mu = S * (1.f/H);
            const float var = Q * (1.f/H) - mu*mu;
            const float rs = rsqrtf(var + LN_EPS);
            #pragma unroll
            for (int nt = 0; nt < 2; ++nt) {
                const float v = fmaxf((acc1[m][nt][rg] - mu) * rs * g1[nt] + bb1[nt], 0.f);
                h1bf[row][32*w + 16*nt + ln] = f2b(v);
            }
        }
    __syncthreads();

    // ---- layer 2: [32,128] @ [128->cols] ----
    f32x4 acc2[2][2];
    #pragma unroll
    for (int m = 0; m < 2; ++m) {
        #pragma unroll
        for (int nt = 0; nt < 2; ++nt) acc2[m][nt] = (f32x4)(0.f);
        bf16x8 af[4];
        #pragma unroll
        for (int kt = 0; kt < 4; ++kt)
            af[kt] = *(const bf16x8*)&h1bf[m*16 + ln][kt*32 + lg*8];
        #pragma unroll
        for (int kt = 0; kt < 4; ++kt)
            #pragma unroll
            for (int nt = 0; nt < 2; ++nt)
                acc2[m][nt] = MFMA16x16x32(af[kt], wf2[nt][kt], acc2[m][nt]);
    }

    // LN2 stats
    #pragma unroll
    for (int m = 0; m < 2; ++m)
        #pragma unroll
        for (int rg = 0; rg < 4; ++rg) {
            float s = 0.f, q = 0.f;
            #pragma unroll
            for (int nt = 0; nt < 2; ++nt) {
                const float a = acc2[m][nt][rg] + b2[nt];
                acc2[m][nt][rg] = a;
                s += a; q += a*a;
            }
            #pragma unroll
            for (int off = 1; off < 16; off <<= 1) {
                s += __shfl_xor(s, off);
                q += __shfl_xor(q, off);
            }
            if (ln == 0) {
                const int row = m*16 + lg*4 + rg;
                redL[w][row][0] = s;
                redL[w][row][1] = q;
            }
        }
    __syncthreads();

    // apply LN2 + relu, layer-3 partial dot
    #pragma unroll
    for (int m = 0; m < 2; ++m)
        #pragma unroll
        for (int rg = 0; rg < 4; ++rg) {
            const int row = m*16 + lg*4 + rg;
            const float S = redL[0][row][0] + redL[1][row][0] + redL[2][row][0] + redL[3][row][0];
            const float Q = redL[0][row][1] + redL[1][row][1] + redL[2][row][1] + redL[3][row][1];
            const float mu = S * (1.f/H);
            const float var = Q * (1.f/H) - mu*mu;
            const float rs = rsqrtf(var + LN_EPS);
            float p = 0.f;
            #pragma unroll
            for (int nt = 0; nt < 2; ++nt) {
                const float v = fmaxf((acc2[m][nt][rg] - mu) * rs * g2[nt] + bb2[nt], 0.f);
                p += v * w3[nt];
            }
            #pragma unroll
            for (int off = 1; off < 16; off <<= 1) p += __shfl_xor(p, off);
            if (ln == 0) red3[w][row] = p;
        }
    __syncthreads();

    if (tid < 32) {
        const int row = tid;
        const float p = red3[0][row] + red3[1][row] + red3[2][row] + red3[3][row] + pi3_b[0];
        const int b = r0 + row;
        const int n = b & (N_AG - 1);
        const int m = b >> 13;
        pi_out[(size_t)n * M_MODES + m] = p;
    }
}

// ===========================================================================
// Fallback (round-1 fused fp32 kernel) — used only if ws_size is tiny.
// ===========================================================================
__global__ __launch_bounds__(128) void gru_heads_kernel(
    const float* __restrict__ local_embed,
    const float* __restrict__ global_embed,
    const float* __restrict__ W_ih,
    const float* __restrict__ W_hh,
    const float* __restrict__ b_ih,
    const float* __restrict__ b_hh,
    const float* __restrict__ loc1_w,
    const float* __restrict__ loc1_b,
    const float* __restrict__ loc_ln_g, const float* __restrict__ loc_ln_b,
    const float* __restrict__ loc2_w,
    const float* __restrict__ loc2_b,
    const float* __restrict__ sc1_w, const float* __restrict__ sc1_b,
    const float* __restrict__ sc_ln_g, const float* __restrict__ sc_ln_b,
    const float* __restrict__ sc2_w, const float* __restrict__ sc2_b,
    float* __restrict__ traj)
{
    __shared__ float hA[ROWS][H];
    __shared__ float hB[ROWS][H];
    __shared__ float lnbuf[ROWS][2][H];
    __shared__ float red[2][ROWS][2][2];

    const int j    = threadIdx.x;
    const int wid  = j >> 6;
    const int lane = j & 63;
    const int b0   = blockIdx.x * ROWS;

    #pragma unroll
    for (int r = 0; r < ROWS; ++r) {
        const int b = b0 + r;
        const int n = b & (N_AG - 1);
        hA[r][j] = local_embed[(size_t)n * H + j];
        lnbuf[r][0][j] = global_embed[(size_t)b * I_DIM + j];
    }
    __syncthreads();

    const float bhr = b_hh[j], bhz = b_hh[H + j], bhn = b_hh[2 * H + j];
    const float lgj = loc_ln_g[j], lbj = loc_ln_b[j];
    const float sgj = sc_ln_g[j],  sbj = sc_ln_b[j];
    const float l1b = loc1_b[j],   s1b = sc1_b[j];

    float gx0[ROWS], gx1[ROWS], gx2[ROWS];
    #pragma unroll
    for (int r = 0; r < ROWS; ++r) { gx0[r] = 0.f; gx1[r] = 0.f; gx2[r] = 0.f; }
    {
        const float4* u0 = (const float4*)(W_ih + (size_t)j * I_DIM);
        const float4* u1 = (const float4*)(W_ih + (size_t)(H + j) * I_DIM);
        const float4* u2 = (const float4*)(W_ih + (size_t)(2 * H + j) * I_DIM);
        #pragma unroll 4
        for (int k4 = 0; k4 < I_DIM / 4; ++k4) {
            const float4 w0 = u0[k4], w1 = u1[k4], w2 = u2[k4];
            #pragma unroll
            for (int r = 0; r < ROWS; ++r) {
                const float4 xv = ((const float4*)(&lnbuf[r][0][0]))[k4];
                gx0[r] += dot4(w0, xv);
                gx1[r] += dot4(w1, xv);
                gx2[r] += dot4(w2, xv);
            }
        }
        const float bi0 = b_ih[j], bi1 = b_ih[H + j], bi2 = b_ih[2 * H + j];
        #pragma unroll
        for (int r = 0; r < ROWS; ++r) { gx0[r] += bi0; gx1[r] += bi1; gx2[r] += bi2; }
    }

    const float4* w0p = (const float4*)(W_hh + (size_t)j * H);
    const float4* w1p = (const float4*)(W_hh + (size_t)(H + j) * H);
    const float4* w2p = (const float4*)(W_hh + (size_t)(2 * H + j) * H);
    const float4* wlp = (const float4*)(loc1_w + (size_t)j * H);
    const float4* wsp = (const float4*)(sc1_w + (size_t)j * H);

    for (int t = 0; t < T_STEPS; ++t) {
        float* hc = (t & 1) ? &hB[0][0] : &hA[0][0];
        float* hn = (t & 1) ? &hA[0][0] : &hB[0][0];

        float ar[ROWS], az[ROWS], an[ROWS];
        #pragma unroll
        for (int r = 0; r < ROWS; ++r) { ar[r] = 0.f; az[r] = 0.f; an[r] = 0.f; }
        #pragma unroll 4
        for (int k4 = 0; k4 < H / 4; ++k4) {
            const float4 w0 = w0p[k4], w1 = w1p[k4], w2 = w2p[k4];
            #pragma unroll
            for (int r = 0; r < ROWS; ++r) {
                const float4 hv = ((const float4*)(hc + r * H))[k4];
                ar[r] += dot4(w0, hv);
                az[r] += dot4(w1, hv);
                an[r] += dot4(w2, hv);
            }
        }

        #pragma unroll
        for (int r = 0; r < ROWS; ++r) {
            const float rr = sigm(gx0[r] + ar[r] + bhr);
            const float zz = sigm(gx1[r] + az[r] + bhz);
            const float nn = tanhf(gx2[r] + rr * (an[r] + bhn));
            const float hold = hc[r * H + j];
            hn[r * H + j] = (1.f - zz) * nn + zz * hold;
        }
        __syncthreads();

        float aL[ROWS], aS[ROWS];
        #pragma unroll
        for (int r = 0; r < ROWS; ++r) { aL[r] = l1b; aS[r] = s1b; }
        #pragma unroll 4
        for (int k4 = 0; k4 < H / 4; ++k4) {
            const float4 wl = wlp[k4], ws = wsp[k4];
            #pragma unroll
            for (int r = 0; r < ROWS; ++r) {
                const float4 hv = ((const float4*)(hn + r * H))[k4];
                aL[r] += dot4(wl, hv);
                aS[r] += dot4(ws, hv);
            }
        }

        #pragma unroll
        for (int r = 0; r < ROWS; ++r) {
            const float sL = wave_sum(aL[r]);
            const float qL = wave_sum(aL[r] * aL[r]);
            const float sS = wave_sum(aS[r]);
            const float qS = wave_sum(aS[r] * aS[r]);
            if (lane == 0) {
                red[wid][r][0][0] = sL; red[wid][r][0][1] = qL;
                red[wid][r][1][0] = sS; red[wid][r][1][1] = qS;
            }
        }
        __syncthreads();

        #pragma unroll
        for (int r = 0; r < ROWS; ++r) {
            const float sL = red[0][r][0][0] + red[1][r][0][0];
            const float qL = red[0][r][0][1] + red[1][r][0][1];
            const float mL = sL * (1.f / H);
            const float vL = qL * (1.f / H) - mL * mL;
            lnbuf[r][0][j] = fmaxf((aL[r] - mL) * rsqrtf(vL + LN_EPS) * lgj + lbj, 0.f);
            const float sS = red[0][r][1][0] + red[1][r][1][0];
            const float qS = red[0][r][1][1] + red[1][r][1][1];
            const float mS = sS * (1.f / H);
            const float vS = qS * (1.f / H) - mS * mS;
            lnbuf[r][1][j] = fmaxf((aS[r] - mS) * rsqrtf(vS + LN_EPS) * sgj + sbj, 0.f);
        }
        __syncthreads();

        if (threadIdx.x < ROWS * 4) {
            const int r = threadIdx.x >> 2;
            const int o = threadIdx.x & 3;
            const int head = (o >> 1);
            const int oo = o & 1;
            const float* w = head ? (sc2_w + oo * H) : (loc2_w + oo * H);
            const float4* w4 = (const float4*)w;
            const float4* v4 = (const float4*)(&lnbuf[r][head][0]);
            float acc = 0.f;
            #pragma unroll
            for (int k4 = 0; k4 < H / 4; ++k4) acc += dot4(w4[k4], v4[k4]);
            acc += head ? sc2_b[oo] : loc2_b[oo];
            if (head) {
                acc = (acc > 0.f ? acc : expm1f(acc)) + 1.0f + MIN_SCALE;
            }
            traj[((size_t)(b0 + r) * T_STEPS + t) * 4 + o] = acc;
        }
    }
}

extern "C" void kernel_launch(void* const* d_in, const int* in_sizes, int n_in,
                              void* d_out, int out_size, void* d_ws, size_t ws_size,
                              hipStream_t stream) {
    (void)in_sizes; (void)n_in; (void)out_size;
    const float* local_embed  = (const float*)d_in[0];
    const float* global_embed = (const float*)d_in[1];
    const float* W_ih   = (const float*)d_in[2];
    const float* W_hh   = (const float*)d_in[3];
    const float* b_ih   = (const float*)d_in[4];
    const float* b_hh   = (const float*)d_in[5];
    const float* loc1_w = (const float*)d_in[6];
    const float* loc1_b = (const float*)d_in[7];
    const float* loc_ln_g = (const float*)d_in[8];
    const float* loc_ln_b = (const float*)d_in[9];
    const float* loc2_w = (const float*)d_in[10];
    const float* loc2_b = (const float*)d_in[11];
    const float* sc1_w  = (const float*)d_in[12];
    const float* sc1_b  = (const float*)d_in[13];
    const float* sc_ln_g = (const float*)d_in[14];
    const float* sc_ln_b = (const float*)d_in[15];
    const float* sc2_w  = (const float*)d_in[16];
    const float* sc2_b  = (const float*)d_in[17];
    const float* pi1_w  = (const float*)d_in[18];
    const float* pi1_b  = (const float*)d_in[19];
    const float* pi_ln1_g = (const float*)d_in[20];
    const float* pi_ln1_b = (const float*)d_in[21];
    const float* pi2_w  = (const float*)d_in[22];
    const float* pi2_b  = (const float*)d_in[23];
    const float* pi_ln2_g = (const float*)d_in[24];
    const float* pi_ln2_b = (const float*)d_in[25];
    const float* pi3_w  = (const float*)d_in[26];
    const float* pi3_b  = (const float*)d_in[27];

    float* traj = (float*)d_out;
    float* pi_out = traj + (size_t)B_TOT * T_STEPS * 4;

    pi_mfma_kernel<<<B_TOT / 32, 256, 0, stream>>>(
        local_embed, global_embed, pi1_w, pi1_b, pi_ln1_g, pi_ln1_b,
        pi2_w, pi2_b, pi_ln2_g, pi_ln2_b, pi3_w, pi3_b, pi_out);

    // h-history (bf16) chunking against workspace size
    const size_t row_bytes = (size_t)T_STEPS * H * sizeof(unsigned short);  // 7680
    long long rc = (long long)(ws_size / row_bytes);
    int Rc = rc > B_TOT ? B_TOT : (int)rc;
    Rc &= ~15;

    if (Rc >= 16) {
        for (int basep = 0; basep < B_TOT; basep += Rc) {
            const int rows = (B_TOT - basep < Rc) ? (B_TOT - basep) : Rc;
            gru_rec_kernel<<<rows / 16, 256, 0, stream>>>(
                local_embed, global_embed, W_ih, W_hh, b_ih, b_hh,
                basep, (unsigned short*)d_ws);
            heads_kernel<<<(rows * T_STEPS) / 32, 256, 0, stream>>>(
                (const unsigned short*)d_ws, basep,
                loc1_w, loc1_b, loc_ln_g, loc_ln_b, loc2_w, loc2_b,
                sc1_w, sc1_b, sc_ln_g, sc_ln_b, sc2_w, sc2_b, traj);
        }
    } else {
        gru_heads_kernel<<<B_TOT / ROWS, 128, 0, stream>>>(
            local_embed, global_embed, W_ih, W_hh, b_ih, b_hh,
            loc1_w, loc1_b, loc_ln_g, loc_ln_b, loc2_w, loc2_b,
            sc1_w, sc1_b, sc_ln_g, sc_ln_b, sc2_w, sc2_b, traj);
    }
}

// Round 4
// 879.711 us; speedup vs baseline: 8.3471x; 1.2534x over previous
//
#include <hip/hip_runtime.h>
#include <math.h>

#define H 128
#define I_DIM 128
#define T_STEPS 30
#define M_MODES 6
#define N_AG 8192
#define B_TOT (M_MODES * N_AG)   /* 49152 */
#define ROWS 16
#define LN_EPS 1e-5f
#define MIN_SCALE 0.001f

typedef short bf16x8 __attribute__((ext_vector_type(8)));
typedef float f32x4 __attribute__((ext_vector_type(4)));

#define MFMA16x16x32(A, B, C) __builtin_amdgcn_mfma_f32_16x16x32_bf16(A, B, C, 0, 0, 0)

__device__ __forceinline__ short f2b(float f) {
    union { float f; unsigned u; } v; v.f = f;
    return (short)((v.u + 0x7FFFu + ((v.u >> 16) & 1u)) >> 16);
}

__device__ __forceinline__ bf16x8 load8_cvt(const float* __restrict__ p) {
    const float4 a = ((const float4*)p)[0];
    const float4 b = ((const float4*)p)[1];
    bf16x8 r;
    r[0]=f2b(a.x); r[1]=f2b(a.y); r[2]=f2b(a.z); r[3]=f2b(a.w);
    r[4]=f2b(b.x); r[5]=f2b(b.y); r[6]=f2b(b.z); r[7]=f2b(b.w);
    return r;
}

__device__ __forceinline__ float fast_sigm(float x) {
    return __builtin_amdgcn_rcpf(1.f + __expf(-x));
}
__device__ __forceinline__ float fast_tanh(float x) {
    return 1.f - 2.f * __builtin_amdgcn_rcpf(1.f + __expf(2.f * x));
}

__device__ __forceinline__ float dot4(float4 a, float4 b) {
    return a.x * b.x + a.y * b.y + a.z * b.z + a.w * b.w;
}

__device__ __forceinline__ float wave_sum(float v) {
    #pragma unroll
    for (int off = 32; off > 0; off >>= 1) v += __shfl_xor(v, off);
    return v;
}

__device__ __forceinline__ float sigm(float x) {
    return 1.0f / (1.0f + expf(-x));
}

// ===========================================================================
// Kernel A: GRU recurrence via MFMA. 256 thr = 4 waves, 16 rows/block.
// ===========================================================================
__global__ __launch_bounds__(256, 2) void gru_rec_kernel(
    const float* __restrict__ local_embed, const float* __restrict__ global_embed,
    const float* __restrict__ W_ih, const float* __restrict__ W_hh,
    const float* __restrict__ b_ih, const float* __restrict__ b_hh,
    int base, unsigned short* __restrict__ hist)
{
    __shared__ short xbuf[16][136];   // padded: row stride 272 B
    __shared__ short hbf[16][136];

    const int tid = threadIdx.x;
    const int w  = tid >> 6;          // wave 0..3
    const int l  = tid & 63;
    const int ln = l & 15;            // lane-in-16 (D col / A row / B col)
    const int lg = l >> 4;            // lane group (D row group / A,B k group)
    const int b0 = base + blockIdx.x * 16;

    // ---- stage x (bf16) and h0 (fp32 regs + bf16 LDS) ----
    float h_reg[2][4];
    #pragma unroll
    for (int u = 0; u < 2; ++u) {
        const int j = 32*w + 16*u + ln;
        #pragma unroll
        for (int rg = 0; rg < 4; ++rg) {
            const int r = lg*4 + rg;
            const int b = b0 + r;
            const int n = b & (N_AG - 1);
            xbuf[r][j] = f2b(global_embed[(size_t)b * I_DIM + j]);
            const float h0 = local_embed[(size_t)n * H + j];
            h_reg[u][rg] = h0;
            hbf[r][j] = f2b(h0);
        }
    }

    // ---- W_ih B-fragments (temporary; overwritten by W_hh below) ----
    bf16x8 wf[3][2][4];
    #pragma unroll
    for (int g = 0; g < 3; ++g)
        #pragma unroll
        for (int u = 0; u < 2; ++u) {
            const int crow = g*H + 32*w + 16*u + ln;
            #pragma unroll
            for (int kt = 0; kt < 4; ++kt)
                wf[g][u][kt] = load8_cvt(W_ih + (size_t)crow * I_DIM + kt*32 + lg*8);
        }

    __syncthreads();

    // ---- gx = x @ W_ih^T + b_ih (once; same input every timestep) ----
    float gx[3][2][4];
    {
        bf16x8 af[4];
        #pragma unroll
        for (int kt = 0; kt < 4; ++kt)
            af[kt] = *(const bf16x8*)&xbuf[ln][kt*32 + lg*8];
        f32x4 acc[3][2];
        #pragma unroll
        for (int g = 0; g < 3; ++g)
            #pragma unroll
            for (int u = 0; u < 2; ++u)
                acc[g][u] = (f32x4)(0.f);
        #pragma unroll
        for (int kt = 0; kt < 4; ++kt)
            #pragma unroll
            for (int g = 0; g < 3; ++g)
                #pragma unroll
                for (int u = 0; u < 2; ++u)
                    acc[g][u] = MFMA16x16x32(af[kt], wf[g][u][kt], acc[g][u]);
        #pragma unroll
        for (int g = 0; g < 3; ++g)
            #pragma unroll
            for (int u = 0; u < 2; ++u) {
                const float bi = b_ih[g*H + 32*w + 16*u + ln];
                #pragma unroll
                for (int rg = 0; rg < 4; ++rg)
                    gx[g][u][rg] = acc[g][u][rg] + bi;
            }
    }

    // ---- W_hh B-fragments + b_hh ----
    float bh[3][2];
    #pragma unroll
    for (int g = 0; g < 3; ++g)
        #pragma unroll
        for (int u = 0; u < 2; ++u) {
            const int crow = g*H + 32*w + 16*u + ln;
            bh[g][u] = b_hh[crow];
            #pragma unroll
            for (int kt = 0; kt < 4; ++kt)
                wf[g][u][kt] = load8_cvt(W_hh + (size_t)crow * H + kt*32 + lg*8);
        }

    const int lb0 = b0 - base;
    const int sr  = tid >> 4;          // store row 0..15
    const int seg = tid & 15;          // store segment 0..15 (8 shorts each)

    for (int t = 0; t < T_STEPS; ++t) {
        // A-frags from h(t-1)
        bf16x8 af[4];
        #pragma unroll
        for (int kt = 0; kt < 4; ++kt)
            af[kt] = *(const bf16x8*)&hbf[ln][kt*32 + lg*8];

        f32x4 ga[3][2];
        #pragma unroll
        for (int g = 0; g < 3; ++g)
            #pragma unroll
            for (int u = 0; u < 2; ++u) ga[g][u] = (f32x4)(0.f);
        #pragma unroll
        for (int kt = 0; kt < 4; ++kt)
            #pragma unroll
            for (int g = 0; g < 3; ++g)
                #pragma unroll
                for (int u = 0; u < 2; ++u)
                    ga[g][u] = MFMA16x16x32(af[kt], wf[g][u][kt], ga[g][u]);

        // gates: fully register-local (r/z/n of hidden unit j share lane+reg)
        unsigned short hb[2][4];
        #pragma unroll
        for (int u = 0; u < 2; ++u) {
            #pragma unroll
            for (int rg = 0; rg < 4; ++rg) {
                const float rr = fast_sigm(gx[0][u][rg] + ga[0][u][rg] + bh[0][u]);
                const float zz = fast_sigm(gx[1][u][rg] + ga[1][u][rg] + bh[1][u]);
                const float nn = fast_tanh(gx[2][u][rg] + rr * (ga[2][u][rg] + bh[2][u]));
                const float h  = (1.f - zz) * nn + zz * h_reg[u][rg];
                h_reg[u][rg] = h;
                hb[u][rg] = (unsigned short)f2b(h);
            }
        }
        __syncthreads();   // all A-frag reads of h(t-1) complete
        #pragma unroll
        for (int u = 0; u < 2; ++u) {
            const int j = 32*w + 16*u + ln;
            #pragma unroll
            for (int rg = 0; rg < 4; ++rg)
                hbf[lg*4 + rg][j] = (short)hb[u][rg];
        }
        __syncthreads();   // h(t) visible for next step + for store

        // coalesced history store: one uint4 per thread, 256B/row contiguous
        const uint4 hv = *(const uint4*)&hbf[sr][seg*8];
        *(uint4*)(hist + (size_t)(lb0 + sr) * (T_STEPS * H) + t * H + seg*8) = hv;
    }
}

// ===========================================================================
// Kernel B: loc/scale heads — weight-stationary persistent blocks.
// 768 blocks x 256 thr (4 waves); waves 0,1 = loc head, waves 2,3 = sc head.
// Each block grid-strides over 32-row tiles; weights live in VGPRs; next
// tile's global loads issued before compute (T14 issue-early/write-late).
// ===========================================================================
__global__ __launch_bounds__(256, 3) void heads_kernel(
    const unsigned short* __restrict__ hist, int base, int ntiles,
    const float* __restrict__ loc1_w, const float* __restrict__ loc1_b,
    const float* __restrict__ loc_ln_g, const float* __restrict__ loc_ln_b,
    const float* __restrict__ loc2_w, const float* __restrict__ loc2_b,
    const float* __restrict__ sc1_w, const float* __restrict__ sc1_b,
    const float* __restrict__ sc_ln_g, const float* __restrict__ sc_ln_b,
    const float* __restrict__ sc2_w, const float* __restrict__ sc2_b,
    float* __restrict__ traj)
{
    __shared__ short habf[32][136];
    __shared__ float red[2][32][4];        // [head][row][s0,q0,s1,q1]
    __shared__ float red2[2][32][2][2];    // [head][row][pairwave][o]

    const int tid = threadIdx.x;
    const int w  = tid >> 6;
    const int l  = tid & 63;
    const int ln = l & 15;
    const int lg = l >> 4;
    const int head = w >> 1;               // 0 = loc, 1 = sc
    const int wp = w & 1;                  // channel half within head

    const float* __restrict__ W1  = head ? sc1_w   : loc1_w;
    const float* __restrict__ B1v = head ? sc1_b   : loc1_b;
    const float* __restrict__ Gv  = head ? sc_ln_g : loc_ln_g;
    const float* __restrict__ Bv  = head ? sc_ln_b : loc_ln_b;
    const float* __restrict__ W2  = head ? sc2_w   : loc2_w;
    const float* __restrict__ B2v = head ? sc2_b   : loc2_b;

    // ---- weights: loaded ONCE per block, stationary in VGPRs ----
    bf16x8 wf[4][4];
    float bias1[4], lng[4], lnb[4], w2a[4], w2b[4];
    #pragma unroll
    for (int nt = 0; nt < 4; ++nt) {
        const int c = 64*wp + 16*nt + ln;
        #pragma unroll
        for (int kt = 0; kt < 4; ++kt)
            wf[nt][kt] = load8_cvt(W1 + (size_t)c * H + kt*32 + lg*8);
        bias1[nt] = B1v[c]; lng[nt] = Gv[c]; lnb[nt] = Bv[c];
        w2a[nt] = W2[c];    w2b[nt] = W2[H + c];
    }
    const float b2_0 = B2v[0], b2_1 = B2v[1];

    // staging indices: thread loads rows (tid>>4) and (tid>>4)+16, seg tid&15
    const int s_r  = tid >> 4;
    const int s_sg = tid & 15;

    // ---- prologue: load tile blockIdx.x ----
    uint4 ld0, ld1;
    {
        const size_t rb = (size_t)blockIdx.x * 32;
        ld0 = *(const uint4*)(hist + (rb + s_r)      * H + s_sg*8);
        ld1 = *(const uint4*)(hist + (rb + s_r + 16) * H + s_sg*8);
    }

    for (int it = blockIdx.x; it < ntiles; it += gridDim.x) {
        __syncthreads();                    // prior tile's LDS reads done
        *(uint4*)&habf[s_r][s_sg*8]      = ld0;
        *(uint4*)&habf[s_r + 16][s_sg*8] = ld1;
        __syncthreads();                    // tile staged

        // issue next tile's loads now; latency hides under compute below
        const int nxt = it + gridDim.x;
        if (nxt < ntiles) {
            const size_t rb = (size_t)nxt * 32;
            ld0 = *(const uint4*)(hist + (rb + s_r)      * H + s_sg*8);
            ld1 = *(const uint4*)(hist + (rb + s_r + 16) * H + s_sg*8);
        }

        // ---- layer-1 GEMM ----
        f32x4 acc[2][4];
        #pragma unroll
        for (int m = 0; m < 2; ++m) {
            #pragma unroll
            for (int nt = 0; nt < 4; ++nt) acc[m][nt] = (f32x4)(0.f);
            bf16x8 af[4];
            #pragma unroll
            for (int kt = 0; kt < 4; ++kt)
                af[kt] = *(const bf16x8*)&habf[m*16 + ln][kt*32 + lg*8];
            #pragma unroll
            for (int kt = 0; kt < 4; ++kt)
                #pragma unroll
                for (int nt = 0; nt < 4; ++nt)
                    acc[m][nt] = MFMA16x16x32(af[kt], wf[nt][kt], acc[m][nt]);
        }

        // ---- bias + LN stats (16-lane shuffle partials) ----
        #pragma unroll
        for (int m = 0; m < 2; ++m)
            #pragma unroll
            for (int rg = 0; rg < 4; ++rg) {
                float s = 0.f, q = 0.f;
                #pragma unroll
                for (int nt = 0; nt < 4; ++nt) {
                    const float a = acc[m][nt][rg] + bias1[nt];
                    acc[m][nt][rg] = a;
                    s += a; q += a*a;
                }
                #pragma unroll
                for (int off = 1; off < 16; off <<= 1) {
                    s += __shfl_xor(s, off);
                    q += __shfl_xor(q, off);
                }
                if (ln == 0) {
                    const int row = m*16 + lg*4 + rg;
                    red[head][row][wp*2+0] = s;
                    red[head][row][wp*2+1] = q;
                }
            }
        __syncthreads();

        // ---- LN + relu + second-linear partials ----
        #pragma unroll
        for (int m = 0; m < 2; ++m)
            #pragma unroll
            for (int rg = 0; rg < 4; ++rg) {
                const int row = m*16 + lg*4 + rg;
                const float4 rv = *(const float4*)&red[head][row][0];
                const float S = rv.x + rv.z, Q = rv.y + rv.w;
                const float mu = S * (1.f/H);
                const float var = Q * (1.f/H) - mu*mu;
                const float rs = rsqrtf(var + LN_EPS);
                float p0 = 0.f, p1 = 0.f;
                #pragma unroll
                for (int nt = 0; nt < 4; ++nt) {
                    float v = (acc[m][nt][rg] - mu) * rs * lng[nt] + lnb[nt];
                    v = fmaxf(v, 0.f);
                    p0 += v * w2a[nt];
                    p1 += v * w2b[nt];
                }
                #pragma unroll
                for (int off = 1; off < 16; off <<= 1) {
                    p0 += __shfl_xor(p0, off);
                    p1 += __shfl_xor(p1, off);
                }
                if (ln == 0) {
                    red2[head][row][wp][0] = p0;
                    red2[head][row][wp][1] = p1;
                }
            }
        __syncthreads();

        // ---- combine wave pair, ELU for scale head, store ----
        if (wp == 0 && ln == 0) {
            const int flat0 = it * 32;
            #pragma unroll
            for (int m = 0; m < 2; ++m)
                #pragma unroll
                for (int rg = 0; rg < 4; ++rg) {
                    const int row = m*16 + lg*4 + rg;
                    const int flat = flat0 + row;
                    const int lb = flat / T_STEPS;
                    const int t = flat - lb * T_STEPS;
                    const int b = base + lb;
                    #pragma unroll
                    for (int o = 0; o < 2; ++o) {
                        float val = red2[head][row][0][o] + red2[head][row][1][o]
                                  + (o ? b2_1 : b2_0);
                        if (head) val = (val > 0.f ? val : expm1f(val)) + 1.0f + MIN_SCALE;
                        traj[((size_t)b * T_STEPS + t) * 4 + head*2 + o] = val;
                    }
                }
        }
    }
}

// ===========================================================================
// Kernel C: pi head via MFMA. 32 rows/block, 256 thr = 4 waves.
// ===========================================================================
__global__ __launch_bounds__(256, 2) void pi_mfma_kernel(
    const float* __restrict__ local_embed, const float* __restrict__ global_embed,
    const float* __restrict__ pi1_w, const float* __restrict__ pi1_b,
    const float* __restrict__ ln1_g, const float* __restrict__ ln1_b,
    const float* __restrict__ pi2_w, const float* __restrict__ pi2_b,
    const float* __restrict__ ln2_g, const float* __restrict__ ln2_b,
    const float* __restrict__ pi3_w, const float* __restrict__ pi3_b,
    float* __restrict__ pi_out)
{
    __shared__ short inbf[32][264];        // 32 rows x 256 cols
    __shared__ short h1bf[32][136];        // 32 rows x 128 cols
    __shared__ float redL[4][32][2];       // [wave][row][s,q]
    __shared__ float red3[4][32];

    const int tid = threadIdx.x;
    const int w  = tid >> 6;
    const int l  = tid & 63;
    const int ln = l & 15;
    const int lg = l >> 4;
    const int r0 = blockIdx.x * 32;

    // ---- stage 32 input rows [local(128) | global(128)] as bf16 ----
    {
        const int r   = tid >> 3;          // 0..31
        const int seg = tid & 7;           // 0..7, 32 cols each
        const int b = r0 + r;
        const int n = b & (N_AG - 1);
        const float* src = (seg < 4) ? (local_embed + (size_t)n * H + seg * 32)
                                     : (global_embed + (size_t)b * I_DIM + (seg - 4) * 32);
        short tmp[32];
        #pragma unroll
        for (int i = 0; i < 8; ++i) {
            const float4 v = ((const float4*)src)[i];
            tmp[i*4+0]=f2b(v.x); tmp[i*4+1]=f2b(v.y); tmp[i*4+2]=f2b(v.z); tmp[i*4+3]=f2b(v.w);
        }
        #pragma unroll
        for (int i = 0; i < 4; ++i)
            *(uint4*)&inbf[r][seg*32 + i*8] = *(uint4*)&tmp[i*8];
    }

    // ---- per-wave column params + weight fragments ----
    bf16x8 wf1[2][8];
    bf16x8 wf2[2][4];
    float b1[2], g1[2], bb1[2], b2[2], g2[2], bb2[2], w3[2];
    #pragma unroll
    for (int nt = 0; nt < 2; ++nt) {
        const int c = 32*w + 16*nt + ln;
        #pragma unroll
        for (int kt = 0; kt < 8; ++kt)
            wf1[nt][kt] = load8_cvt(pi1_w + (size_t)c * (2*H) + kt*32 + lg*8);
        #pragma unroll
        for (int kt = 0; kt < 4; ++kt)
            wf2[nt][kt] = load8_cvt(pi2_w + (size_t)c * H + kt*32 + lg*8);
        b1[nt] = pi1_b[c]; g1[nt] = ln1_g[c]; bb1[nt] = ln1_b[c];
        b2[nt] = pi2_b[c]; g2[nt] = ln2_g[c]; bb2[nt] = ln2_b[c];
        w3[nt] = pi3_w[c];
    }
    __syncthreads();

    // ---- layer 1 ----
    f32x4 acc1[2][2];
    #pragma unroll
    for (int m = 0; m < 2; ++m) {
        #pragma unroll
        for (int nt = 0; nt < 2; ++nt) acc1[m][nt] = (f32x4)(0.f);
        bf16x8 af[8];
        #pragma unroll
        for (int kt = 0; kt < 8; ++kt)
            af[kt] = *(const bf16x8*)&inbf[m*16 + ln][kt*32 + lg*8];
        #pragma unroll
        for (int kt = 0; kt < 8; ++kt)
            #pragma unroll
            for (int nt = 0; nt < 2; ++nt)
                acc1[m][nt] = MFMA16x16x32(af[kt], wf1[nt][kt], acc1[m][nt]);
    }

    #pragma unroll
    for (int m = 0; m < 2; ++m)
        #pragma unroll
        for (int rg = 0; rg < 4; ++rg) {
            float s = 0.f, q = 0.f;
            #pragma unroll
            for (int nt = 0; nt < 2; ++nt) {
                const float a = acc1[m][nt][rg] + b1[nt];
                acc1[m][nt][rg] = a;
                s += a; q += a*a;
            }
            #pragma unroll
            for (int off = 1; off < 16; off <<= 1) {
                s += __shfl_xor(s, off);
                q += __shfl_xor(q, off);
            }
            if (ln == 0) {
                const int row = m*16 + lg*4 + rg;
                redL[w][row][0] = s;
                redL[w][row][1] = q;
            }
        }
    __syncthreads();

    #pragma unroll
    for (int m = 0; m < 2; ++m)
        #pragma unroll
        for (int rg = 0; rg < 4; ++rg) {
            const int row = m*16 + lg*4 + rg;
            const float S = redL[0][row][0] + redL[1][row][0] + redL[2][row][0] + redL[3][row][0];
            const float Q = redL[0][row][1] + redL[1][row][1] + redL[2][row][1] + redL[3][row][1];
            const float mu = S * (1.f/H);
            const float var = Q * (1.f/H) - mu*mu;
            const float rs = rsqrtf(var + LN_EPS);
            #pragma unroll
            for (int nt = 0; nt < 2; ++nt) {
                const float v = fmaxf((acc1[m][nt][rg] - mu) * rs * g1[nt] + bb1[nt], 0.f);
                h1bf[row][32*w + 16*nt + ln] = f2b(v);
            }
        }
    __syncthreads();

    // ---- layer 2 ----
    f32x4 acc2[2][2];
    #pragma unroll
    for (int m = 0; m < 2; ++m) {
        #pragma unroll
        for (int nt = 0; nt < 2; ++nt) acc2[m][nt] = (f32x4)(0.f);
        bf16x8 af[4];
        #pragma unroll
        for (int kt = 0; kt < 4; ++kt)
            af[kt] = *(const bf16x8*)&h1bf[m*16 + ln][kt*32 + lg*8];
        #pragma unroll
        for (int kt = 0; kt < 4; ++kt)
            #pragma unroll
            for (int nt = 0; nt < 2; ++nt)
                acc2[m][nt] = MFMA16x16x32(af[kt], wf2[nt][kt], acc2[m][nt]);
    }

    #pragma unroll
    for (int m = 0; m < 2; ++m)
        #pragma unroll
        for (int rg = 0; rg < 4; ++rg) {
            float s = 0.f, q = 0.f;
            #pragma unroll
            for (int nt = 0; nt < 2; ++nt) {
                const float a = acc2[m][nt][rg] + b2[nt];
                acc2[m][nt][rg] = a;
                s += a; q += a*a;
            }
            #pragma unroll
            for (int off = 1; off < 16; off <<= 1) {
                s += __shfl_xor(s, off);
                q += __shfl_xor(q, off);
            }
            if (ln == 0) {
                const int row = m*16 + lg*4 + rg;
                redL[w][row][0] = s;
                redL[w][row][1] = q;
            }
        }
    __syncthreads();

    #pragma unroll
    for (int m = 0; m < 2; ++m)
        #pragma unroll
        for (int rg = 0; rg < 4; ++rg) {
            const int row = m*16 + lg*4 + rg;
            const float S = redL[0][row][0] + redL[1][row][0] + redL[2][row][0] + redL[3][row][0];
            const float Q = redL[0][row][1] + redL[1][row][1] + redL[2][row][1] + redL[3][row][1];
            const float mu = S * (1.f/H);
            const float var = Q * (1.f/H) - mu*mu;
            const float rs = rsqrtf(var + LN_EPS);
            float p = 0.f;
            #pragma unroll
            for (int nt = 0; nt < 2; ++nt) {
                const float v = fmaxf((acc2[m][nt][rg] - mu) * rs * g2[nt] + bb2[nt], 0.f);
                p += v * w3[nt];
            }
            #pragma unroll
            for (int off = 1; off < 16; off <<= 1) p += __shfl_xor(p, off);
            if (ln == 0) red3[w][row] = p;
        }
    __syncthreads();

    if (tid < 32) {
        const int row = tid;
        const float p = red3[0][row] + red3[1][row] + red3[2][row] + red3[3][row] + pi3_b[0];
        const int b = r0 + row;
        const int n = b & (N_AG - 1);
        const int m = b >> 13;
        pi_out[(size_t)n * M_MODES + m] = p;
    }
}

// ===========================================================================
// Fallback (round-1 fused fp32 kernel) — used only if ws_size is tiny.
// ===========================================================================
__global__ __launch_bounds__(128) void gru_heads_kernel(
    const float* __restrict__ local_embed,
    const float* __restrict__ global_embed,
    const float* __restrict__ W_ih,
    const float* __restrict__ W_hh,
    const float* __restrict__ b_ih,
    const float* __restrict__ b_hh,
    const float* __restrict__ loc1_w,
    const float* __restrict__ loc1_b,
    const float* __restrict__ loc_ln_g, const float* __restrict__ loc_ln_b,
    const float* __restrict__ loc2_w,
    const float* __restrict__ loc2_b,
    const float* __restrict__ sc1_w, const float* __restrict__ sc1_b,
    const float* __restrict__ sc_ln_g, const float* __restrict__ sc_ln_b,
    const float* __restrict__ sc2_w, const float* __restrict__ sc2_b,
    float* __restrict__ traj)
{
    __shared__ float hA[ROWS][H];
    __shared__ float hB[ROWS][H];
    __shared__ float lnbuf[ROWS][2][H];
    __shared__ float red[2][ROWS][2][2];

    const int j    = threadIdx.x;
    const int wid  = j >> 6;
    const int lane = j & 63;
    const int b0   = blockIdx.x * ROWS;

    #pragma unroll
    for (int r = 0; r < ROWS; ++r) {
        const int b = b0 + r;
        const int n = b & (N_AG - 1);
        hA[r][j] = local_embed[(size_t)n * H + j];
        lnbuf[r][0][j] = global_embed[(size_t)b * I_DIM + j];
    }
    __syncthreads();

    const float bhr = b_hh[j], bhz = b_hh[H + j], bhn = b_hh[2 * H + j];
    const float lgj = loc_ln_g[j], lbj = loc_ln_b[j];
    const float sgj = sc_ln_g[j],  sbj = sc_ln_b[j];
    const float l1b = loc1_b[j],   s1b = sc1_b[j];

    float gx0[ROWS], gx1[ROWS], gx2[ROWS];
    #pragma unroll
    for (int r = 0; r < ROWS; ++r) { gx0[r] = 0.f; gx1[r] = 0.f; gx2[r] = 0.f; }
    {
        const float4* u0 = (const float4*)(W_ih + (size_t)j * I_DIM);
        const float4* u1 = (const float4*)(W_ih + (size_t)(H + j) * I_DIM);
        const float4* u2 = (const float4*)(W_ih + (size_t)(2 * H + j) * I_DIM);
        #pragma unroll 4
        for (int k4 = 0; k4 < I_DIM / 4; ++k4) {
            const float4 w0 = u0[k4], w1 = u1[k4], w2 = u2[k4];
            #pragma unroll
            for (int r = 0; r < ROWS; ++r) {
                const float4 xv = ((const float4*)(&lnbuf[r][0][0]))[k4];
                gx0[r] += dot4(w0, xv);
                gx1[r] += dot4(w1, xv);
                gx2[r] += dot4(w2, xv);
            }
        }
        const float bi0 = b_ih[j], bi1 = b_ih[H + j], bi2 = b_ih[2 * H + j];
        #pragma unroll
        for (int r = 0; r < ROWS; ++r) { gx0[r] += bi0; gx1[r] += bi1; gx2[r] += bi2; }
    }

    const float4* w0p = (const float4*)(W_hh + (size_t)j * H);
    const float4* w1p = (const float4*)(W_hh + (size_t)(H + j) * H);
    const float4* w2p = (const float4*)(W_hh + (size_t)(2 * H + j) * H);
    const float4* wlp = (const float4*)(loc1_w + (size_t)j * H);
    const float4* wsp = (const float4*)(sc1_w + (size_t)j * H);

    for (int t = 0; t < T_STEPS; ++t) {
        float* hc = (t & 1) ? &hB[0][0] : &hA[0][0];
        float* hn = (t & 1) ? &hA[0][0] : &hB[0][0];

        float ar[ROWS], az[ROWS], an[ROWS];
        #pragma unroll
        for (int r = 0; r < ROWS; ++r) { ar[r] = 0.f; az[r] = 0.f; an[r] = 0.f; }
        #pragma unroll 4
        for (int k4 = 0; k4 < H / 4; ++k4) {
            const float4 w0 = w0p[k4], w1 = w1p[k4], w2 = w2p[k4];
            #pragma unroll
            for (int r = 0; r < ROWS; ++r) {
                const float4 hv = ((const float4*)(hc + r * H))[k4];
                ar[r] += dot4(w0, hv);
                az[r] += dot4(w1, hv);
                an[r] += dot4(w2, hv);
            }
        }

        #pragma unroll
        for (int r = 0; r < ROWS; ++r) {
            const float rr = sigm(gx0[r] + ar[r] + bhr);
            const float zz = sigm(gx1[r] + az[r] + bhz);
            const float nn = tanhf(gx2[r] + rr * (an[r] + bhn));
            const float hold = hc[r * H + j];
            hn[r * H + j] = (1.f - zz) * nn + zz * hold;
        }
        __syncthreads();

        float aL[ROWS], aS[ROWS];
        #pragma unroll
        for (int r = 0; r < ROWS; ++r) { aL[r] = l1b; aS[r] = s1b; }
        #pragma unroll 4
        for (int k4 = 0; k4 < H / 4; ++k4) {
            const float4 wl = wlp[k4], ws = wsp[k4];
            #pragma unroll
            for (int r = 0; r < ROWS; ++r) {
                const float4 hv = ((const float4*)(hn + r * H))[k4];
                aL[r] += dot4(wl, hv);
                aS[r] += dot4(ws, hv);
            }
        }

        #pragma unroll
        for (int r = 0; r < ROWS; ++r) {
            const float sL = wave_sum(aL[r]);
            const float qL = wave_sum(aL[r] * aL[r]);
            const float sS = wave_sum(aS[r]);
            const float qS = wave_sum(aS[r] * aS[r]);
            if (lane == 0) {
                red[wid][r][0][0] = sL; red[wid][r][0][1] = qL;
                red[wid][r][1][0] = sS; red[wid][r][1][1] = qS;
            }
        }
        __syncthreads();

        #pragma unroll
        for (int r = 0; r < ROWS; ++r) {
            const float sL = red[0][r][0][0] + red[1][r][0][0];
            const float qL = red[0][r][0][1] + red[1][r][0][1];
            const float mL = sL * (1.f / H);
            const float vL = qL * (1.f / H) - mL * mL;
            lnbuf[r][0][j] = fmaxf((aL[r] - mL) * rsqrtf(vL + LN_EPS) * lgj + lbj, 0.f);
            const float sS = red[0][r][1][0] + red[1][r][1][0];
            const float qS = red[0][r][1][1] + red[1][r][1][1];
            const float mS = sS * (1.f / H);
            const float vS = qS * (1.f / H) - mS * mS;
            lnbuf[r][1][j] = fmaxf((aS[r] - mS) * rsqrtf(vS + LN_EPS) * sgj + sbj, 0.f);
        }
        __syncthreads();

        if (threadIdx.x < ROWS * 4) {
            const int r = threadIdx.x >> 2;
            const int o = threadIdx.x & 3;
            const int head = (o >> 1);
            const int oo = o & 1;
            const float* w = head ? (sc2_w + oo * H) : (loc2_w + oo * H);
            const float4* w4 = (const float4*)w;
            const float4* v4 = (const float4*)(&lnbuf[r][head][0]);
            float acc = 0.f;
            #pragma unroll
            for (int k4 = 0; k4 < H / 4; ++k4) acc += dot4(w4[k4], v4[k4]);
            acc += head ? sc2_b[oo] : loc2_b[oo];
            if (head) {
                acc = (acc > 0.f ? acc : expm1f(acc)) + 1.0f + MIN_SCALE;
            }
            traj[((size_t)(b0 + r) * T_STEPS + t) * 4 + o] = acc;
        }
    }
}

extern "C" void kernel_launch(void* const* d_in, const int* in_sizes, int n_in,
                              void* d_out, int out_size, void* d_ws, size_t ws_size,
                              hipStream_t stream) {
    (void)in_sizes; (void)n_in; (void)out_size;
    const float* local_embed  = (const float*)d_in[0];
    const float* global_embed = (const float*)d_in[1];
    const float* W_ih   = (const float*)d_in[2];
    const float* W_hh   = (const float*)d_in[3];
    const float* b_ih   = (const float*)d_in[4];
    const float* b_hh   = (const float*)d_in[5];
    const float* loc1_w = (const float*)d_in[6];
    const float* loc1_b = (const float*)d_in[7];
    const float* loc_ln_g = (const float*)d_in[8];
    const float* loc_ln_b = (const float*)d_in[9];
    const float* loc2_w = (const float*)d_in[10];
    const float* loc2_b = (const float*)d_in[11];
    const float* sc1_w  = (const float*)d_in[12];
    const float* sc1_b  = (const float*)d_in[13];
    const float* sc_ln_g = (const float*)d_in[14];
    const float* sc_ln_b = (const float*)d_in[15];
    const float* sc2_w  = (const float*)d_in[16];
    const float* sc2_b  = (const float*)d_in[17];
    const float* pi1_w  = (const float*)d_in[18];
    const float* pi1_b  = (const float*)d_in[19];
    const float* pi_ln1_g = (const float*)d_in[20];
    const float* pi_ln1_b = (const float*)d_in[21];
    const float* pi2_w  = (const float*)d_in[22];
    const float* pi2_b  = (const float*)d_in[23];
    const float* pi_ln2_g = (const float*)d_in[24];
    const float* pi_ln2_b = (const float*)d_in[25];
    const float* pi3_w  = (const float*)d_in[26];
    const float* pi3_b  = (const float*)d_in[27];

    float* traj = (float*)d_out;
    float* pi_out = traj + (size_t)B_TOT * T_STEPS * 4;

    pi_mfma_kernel<<<B_TOT / 32, 256, 0, stream>>>(
        local_embed, global_embed, pi1_w, pi1_b, pi_ln1_g, pi_ln1_b,
        pi2_w, pi2_b, pi_ln2_g, pi_ln2_b, pi3_w, pi3_b, pi_out);

    // h-history (bf16) chunking against workspace size
    const size_t row_bytes = (size_t)T_STEPS * H * sizeof(unsigned short);  // 7680
    long long rc = (long long)(ws_size / row_bytes);
    int Rc = rc > B_TOT ? B_TOT : (int)rc;
    Rc &= ~15;

    if (Rc >= 16) {
        for (int basep = 0; basep < B_TOT; basep += Rc) {
            const int rows = (B_TOT - basep < Rc) ? (B_TOT - basep) : Rc;
            gru_rec_kernel<<<rows / 16, 256, 0, stream>>>(
                local_embed, global_embed, W_ih, W_hh, b_ih, b_hh,
                basep, (unsigned short*)d_ws);
            const int ntiles = (rows * T_STEPS) / 32;
            const int nblk = ntiles < 768 ? ntiles : 768;
            heads_kernel<<<nblk, 256, 0, stream>>>(
                (const unsigned short*)d_ws, basep, ntiles,
                loc1_w, loc1_b, loc_ln_g, loc_ln_b, loc2_w, loc2_b,
                sc1_w, sc1_b, sc_ln_g, sc_ln_b, sc2_w, sc2_b, traj);
        }
    } else {
        gru_heads_kernel<<<B_TOT / ROWS, 128, 0, stream>>>(
            local_embed, global_embed, W_ih, W_hh, b_ih, b_hh,
            loc1_w, loc1_b, loc_ln_g, loc_ln_b, loc2_w, loc2_b,
            sc1_w, sc1_b, sc_ln_g, sc_ln_b, sc2_w, sc2_b, traj);
    }
}